// Round 1
// baseline (4252.014 us; speedup 1.0000x reference)
//
#include <hip/hip_runtime.h>
#include <hip/hip_bf16.h>
#include <math.h>

typedef __bf16 bf16_t;
typedef __bf16 bf16x8 __attribute__((ext_vector_type(8)));
typedef __bf16 bf16x4 __attribute__((ext_vector_type(4)));
typedef float  f32x4  __attribute__((ext_vector_type(4)));
typedef short  s16x4  __attribute__((ext_vector_type(4)));

#define S_LEN 4096
#define DMODEL 768
#define NHEAD 12
#define NLAYER 12
#define FFDIM 3072

// ---- MFMA helpers -------------------------------------------------------
static __device__ inline f32x4 mfma16x16x16(bf16x4 a, bf16x4 b, f32x4 c) {
#if __has_builtin(__builtin_amdgcn_mfma_f32_16x16x16_bf16)
  return __builtin_amdgcn_mfma_f32_16x16x16_bf16(a, b, c, 0, 0, 0);
#else
  return __builtin_amdgcn_mfma_f32_16x16x16bf16_1k(
      __builtin_bit_cast(s16x4, a), __builtin_bit_cast(s16x4, b), c, 0, 0, 0);
#endif
}

// async global -> LDS, 16B per lane. LDS dest is wave-uniform base + lane*16.
static __device__ inline void gload_lds16(const void* g, void* l) {
  __builtin_amdgcn_global_load_lds(
      (const __attribute__((address_space(1))) void*)g,
      (__attribute__((address_space(3))) void*)l, 16, 0, 0);
}

// ---- pos_ids = cumsum(mask)*mask + 1 (B=1, S=4096) ----------------------
__global__ __launch_bounds__(256) void posid_kernel(const int* __restrict__ m,
                                                    int* __restrict__ pids) {
  __shared__ int ps[256];
  int t = threadIdx.x;
  int base = t * 16;
  int loc[16], mv[16];
  int s = 0;
#pragma unroll
  for (int j = 0; j < 16; ++j) { mv[j] = m[base + j]; s += mv[j]; loc[j] = s; }
  ps[t] = s;
  __syncthreads();
  for (int off = 1; off < 256; off <<= 1) {
    int v = (t >= off) ? ps[t - off] : 0;
    __syncthreads();
    ps[t] += v;
    __syncthreads();
  }
  int pre = t ? ps[t - 1] : 0;
#pragma unroll
  for (int j = 0; j < 16; ++j) pids[base + j] = (pre + loc[j]) * mv[j] + 1;
}

// ---- block reduction helper (256 threads) -------------------------------
__device__ inline float blk_sum(float v, float* sred) {
#pragma unroll
  for (int o = 32; o; o >>= 1) v += __shfl_down(v, o, 64);
  int w = threadIdx.x >> 6;
  __syncthreads();
  if ((threadIdx.x & 63) == 0) sred[w] = v;
  __syncthreads();
  return sred[0] + sred[1] + sred[2] + sred[3];
}

// ---- embedding gather + LN (f32 inputs) ----------------------------------
__global__ __launch_bounds__(256) void embed_kernel(
    const int* __restrict__ ids, const int* __restrict__ pids,
    const float* __restrict__ ew, const float* __restrict__ ep,
    const float* __restrict__ et, const float* __restrict__ g,
    const float* __restrict__ b, float* __restrict__ xf,
    bf16_t* __restrict__ xb) {
  __shared__ float sred[4];
  int s = blockIdx.x, t = threadIdx.x;
  long wb = (long)ids[s] * DMODEL;
  long pb = (long)pids[s] * DMODEL;
  float v[3];
#pragma unroll
  for (int j = 0; j < 3; ++j) {
    int d = t + j * 256;
    v[j] = ew[wb + d] + ep[pb + d] + et[d];
  }
  float mu = blk_sum(v[0] + v[1] + v[2], sred) * (1.0f / 768.0f);
  float ss = 0.f;
#pragma unroll
  for (int j = 0; j < 3; ++j) { v[j] -= mu; ss += v[j] * v[j]; }
  float rs = rsqrtf(blk_sum(ss, sred) * (1.0f / 768.0f) + 1e-5f);
#pragma unroll
  for (int j = 0; j < 3; ++j) {
    int d = t + j * 256;
    float o = v[j] * rs * g[d] + b[d];
    xf[(long)s * DMODEL + d] = o;
    xb[(long)s * DMODEL + d] = (bf16_t)o;
  }
}

// ---- LN over f32 tmp -> xf (f32 master) + xb (bf16 mirror) ---------------
__global__ __launch_bounds__(256) void ln_kernel(
    const float* __restrict__ in, const float* __restrict__ g,
    const float* __restrict__ b, float* __restrict__ xf,
    bf16_t* __restrict__ xb) {
  __shared__ float sred[4];
  int row = blockIdx.x, t = threadIdx.x;
  const float* r = in + (long)row * DMODEL;
  float v[3] = {r[t], r[t + 256], r[t + 512]};
  float mu = blk_sum(v[0] + v[1] + v[2], sred) * (1.0f / 768.0f);
  float ss = 0.f;
#pragma unroll
  for (int j = 0; j < 3; ++j) { v[j] -= mu; ss += v[j] * v[j]; }
  float rs = rsqrtf(blk_sum(ss, sred) * (1.0f / 768.0f) + 1e-5f);
#pragma unroll
  for (int j = 0; j < 3; ++j) {
    int d = t + j * 256;
    float o = v[j] * rs * g[d] + b[d];
    xf[(long)row * DMODEL + d] = o;
    xb[(long)row * DMODEL + d] = (bf16_t)o;
  }
}

// ---- f32 -> bf16 transpose (weights), 64x64 tiles ------------------------
__global__ __launch_bounds__(256) void trc_kernel(const float* __restrict__ src,
                                                  bf16_t* __restrict__ dst,
                                                  int R, int C, long srcStride,
                                                  long dstStride) {
  src += (long)blockIdx.z * srcStride;
  dst += (long)blockIdx.z * dstStride;
  __shared__ float tile[64][65];
  int r0 = blockIdx.y * 64, c0 = blockIdx.x * 64;
  int t = threadIdx.x;
  int tr = t >> 4;
  int tc = (t & 15) * 4;
#pragma unroll
  for (int j = 0; j < 4; ++j) {
    int row = tr + j * 16;
    float4 v = *(const float4*)(src + (long)(r0 + row) * C + c0 + tc);
    tile[row][tc] = v.x; tile[row][tc + 1] = v.y;
    tile[row][tc + 2] = v.z; tile[row][tc + 3] = v.w;
  }
  __syncthreads();
#pragma unroll
  for (int j = 0; j < 4; ++j) {
    int row = tr + j * 16;  // dst row within tile (= src col)
    bf16x4 v;
    v[0] = (bf16_t)tile[tc + 0][row]; v[1] = (bf16_t)tile[tc + 1][row];
    v[2] = (bf16_t)tile[tc + 2][row]; v[3] = (bf16_t)tile[tc + 3][row];
    *(bf16x4*)(dst + (long)(c0 + row) * R + r0 + tc) = v;
  }
}

// ---- bf16 -> bf16 transpose (V), 64x64 tiles ------------------------------
__global__ __launch_bounds__(256) void tr_kernel(const bf16_t* __restrict__ src,
                                                 bf16_t* __restrict__ dst,
                                                 int R, int C) {
  __shared__ bf16_t tile[64][68];
  int r0 = blockIdx.y * 64, c0 = blockIdx.x * 64;
  int t = threadIdx.x;
  int tr = t >> 4;
  int tc = (t & 15) * 4;
#pragma unroll
  for (int j = 0; j < 4; ++j) {
    int row = tr + j * 16;
    bf16x4 v = *(const bf16x4*)(src + (long)(r0 + row) * C + c0 + tc);
    tile[row][tc] = v[0]; tile[row][tc + 1] = v[1];
    tile[row][tc + 2] = v[2]; tile[row][tc + 3] = v[3];
  }
  __syncthreads();
#pragma unroll
  for (int j = 0; j < 4; ++j) {
    int row = tr + j * 16;
    bf16x4 v;
    v[0] = tile[tc + 0][row]; v[1] = tile[tc + 1][row];
    v[2] = tile[tc + 2][row]; v[3] = tile[tc + 3][row];
    *(bf16x4*)(dst + (long)(c0 + row) * R + r0 + tc) = v;
  }
}

// ---- main GEMM: C = A(MxK) * Bt(NxK)^T + bias, 128x128 tile, BK=64 -------
// Double-buffered LDS, async global_load_lds staging, counted vmcnt waits.
// At 1 block/CU (192-block grids) there is no inter-block overlap, so the
// intra-block pipeline is what hides HBM latency.
// EP 0: out = bf16(acc + bias)          (QKV; z batches over 3 weight sets)
// EP 1: out = bf16(gelu(acc + bias))    (FF1)
// EP 2: tmp = acc + bias + resf         (attn-out proj / FF2, f32 out)
template <int EP>
__global__ __launch_bounds__(256) void gemm_kernel(
    const bf16_t* __restrict__ A, const bf16_t* __restrict__ Bt, long btStride,
    const float* b0, const float* b1, const float* b2,
    bf16_t* __restrict__ out, long outStride, const float* __restrict__ resf,
    float* __restrict__ tmp, int M, int N, int K) {
  int z = blockIdx.z;
  Bt += (long)z * btStride;
  const float* bias = (z == 0) ? b0 : (z == 1 ? b1 : b2);
  out += (long)z * outStride;

  // layout (per buffer): [k-octet g(0..7)][row(0..127)] x 8 contiguous bf16
  __shared__ __align__(16) bf16_t As[2][128 * 64];
  __shared__ __align__(16) bf16_t Bs[2][128 * 64];

  int tid = threadIdx.x;
  int lane = tid & 63;
  int wave = tid >> 6;
  int wm = (wave >> 1) * 64;
  int wn = (wave & 1) * 64;
  int l15 = lane & 15;
  int g4 = lane >> 4;
  int m0 = blockIdx.y * 128;
  int n0 = blockIdx.x * 128;

  f32x4 acc[4][4] = {};

  // per wave: 4 A-issues + 4 B-issues of 1KB each (64 lanes x 16B) = 8 loads.
  // LDS slot L = c*256 + wave*64 + lane -> identical layout to the reg-staged
  // version (lane's 16B lands at As+L*8); source address also identical.
  auto stage = [&](int buf, int kt) {
#pragma unroll
    for (int c = 0; c < 4; ++c) {
      int L0 = c * 256 + wave * 64;       // wave-uniform LDS base (in 16B units)
      int row = (L0 & 127) + lane;        // lane's source row
      int gg = L0 >> 7;                   // k-octet for this issue
      gload_lds16(A + (long)(m0 + row) * K + kt + gg * 8, As[buf] + L0 * 8);
      gload_lds16(Bt + (long)(n0 + row) * K + kt + gg * 8, Bs[buf] + L0 * 8);
    }
  };

  int nk = K >> 6;
  stage(0, 0);
  int buf = 0;
  for (int it = 0; it < nk; ++it) {
    if (it + 1 < nk) {
      stage(buf ^ 1, (it + 1) << 6);
      // wait only for current tile's 8 loads; next tile's 8 stay in flight
      asm volatile("s_waitcnt vmcnt(8)" ::: "memory");
    } else {
      asm volatile("s_waitcnt vmcnt(0)" ::: "memory");
    }
    __builtin_amdgcn_s_barrier();
    __builtin_amdgcn_sched_barrier(0);  // keep ds_read strictly after barrier
#pragma unroll
    for (int ks = 0; ks < 2; ++ks) {
      bf16x8 af[4], bfr[4];
#pragma unroll
      for (int mt = 0; mt < 4; ++mt)
        af[mt] = *(const bf16x8*)(As[buf] +
                                  (((ks * 4 + g4) * 128) + wm + mt * 16 + l15) * 8);
#pragma unroll
      for (int nt = 0; nt < 4; ++nt)
        bfr[nt] = *(const bf16x8*)(Bs[buf] +
                                   (((ks * 4 + g4) * 128) + wn + nt * 16 + l15) * 8);
#pragma unroll
      for (int mt = 0; mt < 4; ++mt)
#pragma unroll
        for (int nt = 0; nt < 4; ++nt)
          acc[mt][nt] = __builtin_amdgcn_mfma_f32_16x16x32_bf16(
              af[mt], bfr[nt], acc[mt][nt], 0, 0, 0);
    }
    __builtin_amdgcn_sched_barrier(0);  // keep ds_read strictly before barrier
    __builtin_amdgcn_s_barrier();       // all waves done reading buf
    buf ^= 1;
  }

#pragma unroll
  for (int mt = 0; mt < 4; ++mt)
#pragma unroll
    for (int nt = 0; nt < 4; ++nt) {
      int col = n0 + wn + nt * 16 + l15;
      float bval = bias[col];
#pragma unroll
      for (int r = 0; r < 4; ++r) {
        int row = m0 + wm + mt * 16 + g4 * 4 + r;
        float v = acc[mt][nt][r] + bval;
        if (EP == 0) {
          out[(long)row * N + col] = (bf16_t)v;
        } else if (EP == 1) {
          float ge = 0.5f * v * (1.0f + erff(v * 0.70710678118654752f));
          out[(long)row * N + col] = (bf16_t)ge;
        } else {
          tmp[(long)row * N + col] = v + resf[(long)row * N + col];
        }
      }
    }
}

// ---- sliding-window flash attention --------------------------------------
// grid (S/64, H), block 64 (1 wave). q,k: (S,768) bf16; vt: (768,S) bf16.
#define NEGM 30000.0f
__global__ __launch_bounds__(64) void attn_kernel(
    const bf16_t* __restrict__ q, const bf16_t* __restrict__ k,
    const bf16_t* __restrict__ vt, bf16_t* __restrict__ outb) {
  int qt = blockIdx.x * 64;
  int hcol = blockIdx.y * 64;
  int lane = threadIdx.x;
  int l15 = lane & 15, g4 = lane >> 4;
  __shared__ __align__(16) float sbuf[64];

  // Q fragments (B-operand of St = K @ Q^T), scale 1/8 folded in (exact).
  bf16x8 qf[4][2];
#pragma unroll
  for (int nt = 0; nt < 4; ++nt)
#pragma unroll
    for (int ks = 0; ks < 2; ++ks) {
      bf16x8 t = *(const bf16x8*)(q + (long)(qt + nt * 16 + l15) * DMODEL +
                                  hcol + ks * 32 + g4 * 8);
#pragma unroll
      for (int i = 0; i < 8; ++i) t[i] = (bf16_t)((float)t[i] * 0.125f);
      qf[nt][ks] = t;
    }

  f32x4 o[4][4] = {};   // [qmt][dt]; lane r -> O[q=16qmt+4g4+r][d=16dt+l15]
  float mS[4], lS[4];
#pragma unroll
  for (int nt = 0; nt < 4; ++nt) { mS[nt] = -NEGM; lS[nt] = 0.f; }

  int kstart = qt - 256; if (kstart < 0) kstart = 0;
  int kend = qt + 320; if (kend > S_LEN) kend = S_LEN;

  for (int kb = kstart; kb < kend; kb += 64) {
    // St = K_chunk @ Q^T -> St[key=16kt+4g4+r][q=16nt+l15]
    bf16x8 kf[4][2];
#pragma unroll
    for (int kt = 0; kt < 4; ++kt)
#pragma unroll
      for (int ks = 0; ks < 2; ++ks)
        kf[kt][ks] = *(const bf16x8*)(k + (long)(kb + kt * 16 + l15) * DMODEL +
                                      hcol + ks * 32 + g4 * 8);
    f32x4 st[4][4] = {};
#pragma unroll
    for (int kt = 0; kt < 4; ++kt)
#pragma unroll
      for (int nt = 0; nt < 4; ++nt) {
        st[kt][nt] = __builtin_amdgcn_mfma_f32_16x16x32_bf16(
            kf[kt][0], qf[nt][0], st[kt][nt], 0, 0, 0);
        st[kt][nt] = __builtin_amdgcn_mfma_f32_16x16x32_bf16(
            kf[kt][1], qf[nt][1], st[kt][nt], 0, 0, 0);
      }
    // band mask + online softmax stats (per query q = 16nt + l15)
    float alpha[4];
#pragma unroll
    for (int nt = 0; nt < 4; ++nt) {
      int qg = qt + nt * 16 + l15;
      float mx = -NEGM;
#pragma unroll
      for (int kt = 0; kt < 4; ++kt)
#pragma unroll
        for (int r = 0; r < 4; ++r) {
          int kg = kb + kt * 16 + g4 * 4 + r;
          bool valid = (kg >= qg - 256) && (kg <= qg + 256);
          float s = valid ? st[kt][nt][r] : -NEGM;
          st[kt][nt][r] = s;
          mx = fmaxf(mx, s);
        }
      mx = fmaxf(mx, __shfl_xor(mx, 16, 64));
      mx = fmaxf(mx, __shfl_xor(mx, 32, 64));
      float mnew = fmaxf(mS[nt], mx);
      alpha[nt] = exp2f((mS[nt] - mnew) * 1.44269504088896f);
      float ls = 0.f;
#pragma unroll
      for (int kt = 0; kt < 4; ++kt)
#pragma unroll
        for (int r = 0; r < 4; ++r) {
          float p = exp2f((st[kt][nt][r] - mnew) * 1.44269504088896f);
          st[kt][nt][r] = p;
          ls += p;
        }
      ls += __shfl_xor(ls, 16, 64);
      ls += __shfl_xor(ls, 32, 64);
      lS[nt] = lS[nt] * alpha[nt] + ls;
      mS[nt] = mnew;
    }
    // broadcast alpha into O-layout
    if (g4 == 0) {
#pragma unroll
      for (int nt = 0; nt < 4; ++nt) sbuf[nt * 16 + l15] = alpha[nt];
    }
    __syncthreads();
    f32x4 av[4];
#pragma unroll
    for (int qmt = 0; qmt < 4; ++qmt)
      av[qmt] = *(const f32x4*)(sbuf + qmt * 16 + g4 * 4);
#pragma unroll
    for (int qmt = 0; qmt < 4; ++qmt)
#pragma unroll
      for (int dt = 0; dt < 4; ++dt)
#pragma unroll
        for (int r = 0; r < 4; ++r) o[qmt][dt][r] *= av[qmt][r];
    // PV: St lanes are already exactly the A-operand of 16x16x16 MFMA.
#pragma unroll
    for (int kt = 0; kt < 4; ++kt) {
      bf16x4 pa[4];
#pragma unroll
      for (int qmt = 0; qmt < 4; ++qmt)
#pragma unroll
        for (int i = 0; i < 4; ++i) pa[qmt][i] = (bf16_t)st[kt][qmt][i];
      bf16x4 vf[4];
#pragma unroll
      for (int dt = 0; dt < 4; ++dt)
        vf[dt] = *(const bf16x4*)(vt + (long)(hcol + dt * 16 + l15) * S_LEN +
                                  kb + kt * 16 + g4 * 4);
#pragma unroll
      for (int qmt = 0; qmt < 4; ++qmt)
#pragma unroll
        for (int dt = 0; dt < 4; ++dt)
          o[qmt][dt] = mfma16x16x16(pa[qmt], vf[dt], o[qmt][dt]);
    }
    __syncthreads();
  }
  // final normalize by l
  if (g4 == 0) {
#pragma unroll
    for (int nt = 0; nt < 4; ++nt) sbuf[nt * 16 + l15] = lS[nt];
  }
  __syncthreads();
  f32x4 lv[4];
#pragma unroll
  for (int qmt = 0; qmt < 4; ++qmt)
    lv[qmt] = *(const f32x4*)(sbuf + qmt * 16 + g4 * 4);
#pragma unroll
  for (int qmt = 0; qmt < 4; ++qmt)
#pragma unroll
    for (int dt = 0; dt < 4; ++dt)
#pragma unroll
      for (int r = 0; r < 4; ++r)
        outb[(long)(qt + qmt * 16 + g4 * 4 + r) * DMODEL + hcol + dt * 16 +
             l15] = (bf16_t)(o[qmt][dt][r] / lv[qmt][r]);
}

// ---- classifier heads (f32 weights, f32 out) ------------------------------
__global__ __launch_bounds__(256) void cls_kernel(
    const float* __restrict__ xf, const float* cW1, const float* cb1,
    const float* cW2, const float* cb2, const float* dW1,
    const float* db1, const float* dW2, const float* db2,
    float* __restrict__ out) {
  __shared__ float pooled[768];
  __shared__ float hbuf[512];
  int t = threadIdx.x;
  bool dec = (blockIdx.x == 1);
  const float* W1 = dec ? dW1 : cW1;
  const float* B1 = dec ? db1 : cb1;
  const float* W2 = dec ? dW2 : cW2;
  const float* B2 = dec ? db2 : cb2;
  int nout = dec ? 10 : 5;
  float* op = out + (dec ? 5 : 0);
#pragma unroll
  for (int j = 0; j < 3; ++j) pooled[t + j * 256] = xf[t + j * 256];
  __syncthreads();
  for (int n = t; n < 512; n += 256) {
    float a = B1[n];
    for (int k2 = 0; k2 < 768; ++k2)
      a += pooled[k2] * W1[(long)k2 * 512 + n];
    hbuf[n] = fmaxf(a, 0.f);
  }
  __syncthreads();
  if (t < nout) {
    float a = B2[t];
    for (int i = 0; i < 512; ++i) a += hbuf[i] * W2[i * nout + t];
    op[t] = a;
  }
}

// ---- host orchestration --------------------------------------------------
extern "C" void kernel_launch(void* const* d_in, const int* in_sizes, int n_in,
                              void* d_out, int out_size, void* d_ws,
                              size_t ws_size, hipStream_t stream) {
  const int* ids = (const int*)d_in[0];
  const int* amask = (const int*)d_in[1];
  const float* emb_word = (const float*)d_in[2];
  const float* emb_pos = (const float*)d_in[3];
  const float* emb_type = (const float*)d_in[4];
  const float* emb_g = (const float*)d_in[5];
  const float* emb_b = (const float*)d_in[6];
  const float* Wq = (const float*)d_in[7];
  const float* bq = (const float*)d_in[8];
  const float* Wk = (const float*)d_in[9];
  const float* bk = (const float*)d_in[10];
  const float* Wv = (const float*)d_in[11];
  const float* bv = (const float*)d_in[12];
  const float* Wo = (const float*)d_in[13];
  const float* bo = (const float*)d_in[14];
  const float* ln1g = (const float*)d_in[15];
  const float* ln1b = (const float*)d_in[16];
  const float* W1 = (const float*)d_in[17];
  const float* b1 = (const float*)d_in[18];
  const float* W2 = (const float*)d_in[19];
  const float* b2 = (const float*)d_in[20];
  const float* ln2g = (const float*)d_in[21];
  const float* ln2b = (const float*)d_in[22];
  const float* cW1 = (const float*)d_in[23];
  const float* cb1 = (const float*)d_in[24];
  const float* cW2 = (const float*)d_in[25];
  const float* cb2 = (const float*)d_in[26];
  const float* dW1 = (const float*)d_in[27];
  const float* db1 = (const float*)d_in[28];
  const float* dW2 = (const float*)d_in[29];
  const float* db2 = (const float*)d_in[30];
  float* outp = (float*)d_out;

  const size_t SD = (size_t)S_LEN * DMODEL;
  const size_t DD = (size_t)DMODEL * DMODEL;
  const size_t DF = (size_t)DMODEL * FFDIM;
  const size_t SF = (size_t)S_LEN * FFDIM;

  char* p = (char*)d_ws;
  auto carve = [&](size_t bytes) {
    char* r = p;
    p += (bytes + 255) & ~(size_t)255;
    return (void*)r;
  };

  size_t actsBytes = SD * 2 + SD * 4 + 3 * SD * 2 + SD * 2 + SD * 2 + SF * 2 +
                     SD * 4 + S_LEN * 4 + 16 * 256;
  size_t fullW = (36 * DD + 12 * DD + 24 * DF) * 2 + 16 * 256;
  bool full = ws_size >= actsBytes + fullW;

  bf16_t *qkvt, *wot, *w1t, *w2t;
  if (full) {
    qkvt = (bf16_t*)carve(36 * DD * 2);
    wot = (bf16_t*)carve(12 * DD * 2);
    w1t = (bf16_t*)carve(12 * DF * 2);
    w2t = (bf16_t*)carve(12 * DF * 2);
  } else {
    qkvt = (bf16_t*)carve(3 * DD * 2);
    wot = (bf16_t*)carve(DD * 2);
    w1t = (bf16_t*)carve(DF * 2);
    w2t = (bf16_t*)carve(DF * 2);
  }
  bf16_t* xb = (bf16_t*)carve(SD * 2);
  float* xf = (float*)carve(SD * 4);
  bf16_t* qkv = (bf16_t*)carve(3 * SD * 2);
  bf16_t* vt = (bf16_t*)carve(SD * 2);
  bf16_t* attnb = (bf16_t*)carve(SD * 2);
  bf16_t* hbuf = (bf16_t*)carve(SF * 2);
  float* tmp = (float*)carve(SD * 4);
  int* pids = (int*)carve(S_LEN * 4);

  posid_kernel<<<1, 256, 0, stream>>>(amask, pids);
  embed_kernel<<<S_LEN, 256, 0, stream>>>(ids, pids, emb_word, emb_pos,
                                          emb_type, emb_g, emb_b, xf, xb);

  if (full) {
    trc_kernel<<<dim3(12, 12, 12), 256, 0, stream>>>(Wq, qkvt, 768, 768, DD, 3 * DD);
    trc_kernel<<<dim3(12, 12, 12), 256, 0, stream>>>(Wk, qkvt + DD, 768, 768, DD, 3 * DD);
    trc_kernel<<<dim3(12, 12, 12), 256, 0, stream>>>(Wv, qkvt + 2 * DD, 768, 768, DD, 3 * DD);
    trc_kernel<<<dim3(12, 12, 12), 256, 0, stream>>>(Wo, wot, 768, 768, DD, DD);
    trc_kernel<<<dim3(48, 12, 12), 256, 0, stream>>>(W1, w1t, 768, 3072, DF, DF);
    trc_kernel<<<dim3(12, 48, 12), 256, 0, stream>>>(W2, w2t, 3072, 768, DF, DF);
  }

  for (int i = 0; i < NLAYER; ++i) {
    const bf16_t *qkvt_i, *wot_i, *w1t_i, *w2t_i;
    if (full) {
      qkvt_i = qkvt + (size_t)i * 3 * DD;
      wot_i = wot + (size_t)i * DD;
      w1t_i = w1t + (size_t)i * DF;
      w2t_i = w2t + (size_t)i * DF;
    } else {
      trc_kernel<<<dim3(12, 12, 1), 256, 0, stream>>>(Wq + (size_t)i * DD, qkvt, 768, 768, 0, 0);
      trc_kernel<<<dim3(12, 12, 1), 256, 0, stream>>>(Wk + (size_t)i * DD, qkvt + DD, 768, 768, 0, 0);
      trc_kernel<<<dim3(12, 12, 1), 256, 0, stream>>>(Wv + (size_t)i * DD, qkvt + 2 * DD, 768, 768, 0, 0);
      trc_kernel<<<dim3(12, 12, 1), 256, 0, stream>>>(Wo + (size_t)i * DD, wot, 768, 768, 0, 0);
      trc_kernel<<<dim3(48, 12, 1), 256, 0, stream>>>(W1 + (size_t)i * DF, w1t, 768, 3072, 0, 0);
      trc_kernel<<<dim3(12, 48, 1), 256, 0, stream>>>(W2 + (size_t)i * DF, w2t, 3072, 768, 0, 0);
      qkvt_i = qkvt; wot_i = wot; w1t_i = w1t; w2t_i = w2t;
    }
    gemm_kernel<0><<<dim3(6, 32, 3), 256, 0, stream>>>(
        xb, qkvt_i, (long)DD, bq + i * 768, bk + i * 768, bv + i * 768, qkv,
        (long)SD, nullptr, nullptr, S_LEN, 768, 768);
    tr_kernel<<<dim3(12, 64, 1), 256, 0, stream>>>(qkv + 2 * SD, vt, 4096, 768);
    attn_kernel<<<dim3(64, 12), 64, 0, stream>>>(qkv, qkv + SD, vt, attnb);
    gemm_kernel<2><<<dim3(6, 32, 1), 256, 0, stream>>>(
        attnb, wot_i, 0, bo + i * 768, nullptr, nullptr, nullptr, 0, xf, tmp,
        S_LEN, 768, 768);
    ln_kernel<<<S_LEN, 256, 0, stream>>>(tmp, ln1g + i * 768, ln1b + i * 768, xf, xb);
    gemm_kernel<1><<<dim3(24, 32, 1), 256, 0, stream>>>(
        xb, w1t_i, 0, b1 + (size_t)i * FFDIM, nullptr, nullptr, hbuf, 0,
        nullptr, nullptr, S_LEN, FFDIM, 768);
    gemm_kernel<2><<<dim3(6, 32, 1), 256, 0, stream>>>(
        hbuf, w2t_i, 0, b2 + i * 768, nullptr, nullptr, nullptr, 0, xf, tmp,
        S_LEN, 768, FFDIM);
    ln_kernel<<<S_LEN, 256, 0, stream>>>(tmp, ln2g + i * 768, ln2b + i * 768, xf, xb);
  }
  cls_kernel<<<2, 256, 0, stream>>>(xf, cW1, cb1, cW2, cb2, dW1, db1, dW2, db2, outp);
}

// Round 2
// 4088.707 us; speedup vs baseline: 1.0399x; 1.0399x over previous
//
#include <hip/hip_runtime.h>
#include <hip/hip_bf16.h>
#include <math.h>

typedef __bf16 bf16_t;
typedef __bf16 bf16x8 __attribute__((ext_vector_type(8)));
typedef __bf16 bf16x4 __attribute__((ext_vector_type(4)));
typedef float  f32x4  __attribute__((ext_vector_type(4)));
typedef short  s16x4  __attribute__((ext_vector_type(4)));

#define S_LEN 4096
#define DMODEL 768
#define NHEAD 12
#define NLAYER 12
#define FFDIM 3072

// ---- MFMA helpers -------------------------------------------------------
static __device__ inline f32x4 mfma16x16x16(bf16x4 a, bf16x4 b, f32x4 c) {
#if __has_builtin(__builtin_amdgcn_mfma_f32_16x16x16_bf16)
  return __builtin_amdgcn_mfma_f32_16x16x16_bf16(a, b, c, 0, 0, 0);
#else
  return __builtin_amdgcn_mfma_f32_16x16x16bf16_1k(
      __builtin_bit_cast(s16x4, a), __builtin_bit_cast(s16x4, b), c, 0, 0, 0);
#endif
}

// async global -> LDS, 16B per lane. LDS dest is wave-uniform base + lane*16.
static __device__ inline void gload_lds16(const void* g, void* l) {
  __builtin_amdgcn_global_load_lds(
      (const __attribute__((address_space(1))) void*)g,
      (__attribute__((address_space(3))) void*)l, 16, 0, 0);
}

// ---- pos_ids = cumsum(mask)*mask + 1 (B=1, S=4096) ----------------------
__global__ __launch_bounds__(256) void posid_kernel(const int* __restrict__ m,
                                                    int* __restrict__ pids) {
  __shared__ int ps[256];
  int t = threadIdx.x;
  int base = t * 16;
  int loc[16], mv[16];
  int s = 0;
#pragma unroll
  for (int j = 0; j < 16; ++j) { mv[j] = m[base + j]; s += mv[j]; loc[j] = s; }
  ps[t] = s;
  __syncthreads();
  for (int off = 1; off < 256; off <<= 1) {
    int v = (t >= off) ? ps[t - off] : 0;
    __syncthreads();
    ps[t] += v;
    __syncthreads();
  }
  int pre = t ? ps[t - 1] : 0;
#pragma unroll
  for (int j = 0; j < 16; ++j) pids[base + j] = (pre + loc[j]) * mv[j] + 1;
}

// ---- block reduction helper (256 threads) -------------------------------
__device__ inline float blk_sum(float v, float* sred) {
#pragma unroll
  for (int o = 32; o; o >>= 1) v += __shfl_down(v, o, 64);
  int w = threadIdx.x >> 6;
  __syncthreads();
  if ((threadIdx.x & 63) == 0) sred[w] = v;
  __syncthreads();
  return sred[0] + sred[1] + sred[2] + sred[3];
}

// ---- embedding gather + LN (f32 inputs) ----------------------------------
__global__ __launch_bounds__(256) void embed_kernel(
    const int* __restrict__ ids, const int* __restrict__ pids,
    const float* __restrict__ ew, const float* __restrict__ ep,
    const float* __restrict__ et, const float* __restrict__ g,
    const float* __restrict__ b, float* __restrict__ xf,
    bf16_t* __restrict__ xb) {
  __shared__ float sred[4];
  int s = blockIdx.x, t = threadIdx.x;
  long wb = (long)ids[s] * DMODEL;
  long pb = (long)pids[s] * DMODEL;
  float v[3];
#pragma unroll
  for (int j = 0; j < 3; ++j) {
    int d = t + j * 256;
    v[j] = ew[wb + d] + ep[pb + d] + et[d];
  }
  float mu = blk_sum(v[0] + v[1] + v[2], sred) * (1.0f / 768.0f);
  float ss = 0.f;
#pragma unroll
  for (int j = 0; j < 3; ++j) { v[j] -= mu; ss += v[j] * v[j]; }
  float rs = rsqrtf(blk_sum(ss, sred) * (1.0f / 768.0f) + 1e-5f);
#pragma unroll
  for (int j = 0; j < 3; ++j) {
    int d = t + j * 256;
    float o = v[j] * rs * g[d] + b[d];
    xf[(long)s * DMODEL + d] = o;
    xb[(long)s * DMODEL + d] = (bf16_t)o;
  }
}

// ---- LN over f32 tmp -> xf (f32 master) + xb (bf16 mirror) ---------------
__global__ __launch_bounds__(256) void ln_kernel(
    const float* __restrict__ in, const float* __restrict__ g,
    const float* __restrict__ b, float* __restrict__ xf,
    bf16_t* __restrict__ xb) {
  __shared__ float sred[4];
  int row = blockIdx.x, t = threadIdx.x;
  const float* r = in + (long)row * DMODEL;
  float v[3] = {r[t], r[t + 256], r[t + 512]};
  float mu = blk_sum(v[0] + v[1] + v[2], sred) * (1.0f / 768.0f);
  float ss = 0.f;
#pragma unroll
  for (int j = 0; j < 3; ++j) { v[j] -= mu; ss += v[j] * v[j]; }
  float rs = rsqrtf(blk_sum(ss, sred) * (1.0f / 768.0f) + 1e-5f);
#pragma unroll
  for (int j = 0; j < 3; ++j) {
    int d = t + j * 256;
    float o = v[j] * rs * g[d] + b[d];
    xf[(long)row * DMODEL + d] = o;
    xb[(long)row * DMODEL + d] = (bf16_t)o;
  }
}

// ---- f32 -> bf16 transpose (weights), 64x64 tiles ------------------------
__global__ __launch_bounds__(256) void trc_kernel(const float* __restrict__ src,
                                                  bf16_t* __restrict__ dst,
                                                  int R, int C, long srcStride,
                                                  long dstStride) {
  src += (long)blockIdx.z * srcStride;
  dst += (long)blockIdx.z * dstStride;
  __shared__ float tile[64][65];
  int r0 = blockIdx.y * 64, c0 = blockIdx.x * 64;
  int t = threadIdx.x;
  int tr = t >> 4;
  int tc = (t & 15) * 4;
#pragma unroll
  for (int j = 0; j < 4; ++j) {
    int row = tr + j * 16;
    float4 v = *(const float4*)(src + (long)(r0 + row) * C + c0 + tc);
    tile[row][tc] = v.x; tile[row][tc + 1] = v.y;
    tile[row][tc + 2] = v.z; tile[row][tc + 3] = v.w;
  }
  __syncthreads();
#pragma unroll
  for (int j = 0; j < 4; ++j) {
    int row = tr + j * 16;  // dst row within tile (= src col)
    bf16x4 v;
    v[0] = (bf16_t)tile[tc + 0][row]; v[1] = (bf16_t)tile[tc + 1][row];
    v[2] = (bf16_t)tile[tc + 2][row]; v[3] = (bf16_t)tile[tc + 3][row];
    *(bf16x4*)(dst + (long)(c0 + row) * R + r0 + tc) = v;
  }
}

// ---- bf16 -> bf16 transpose (V), 64x64 tiles ------------------------------
__global__ __launch_bounds__(256) void tr_kernel(const bf16_t* __restrict__ src,
                                                 bf16_t* __restrict__ dst,
                                                 int R, int C) {
  __shared__ bf16_t tile[64][68];
  int r0 = blockIdx.y * 64, c0 = blockIdx.x * 64;
  int t = threadIdx.x;
  int tr = t >> 4;
  int tc = (t & 15) * 4;
#pragma unroll
  for (int j = 0; j < 4; ++j) {
    int row = tr + j * 16;
    bf16x4 v = *(const bf16x4*)(src + (long)(r0 + row) * C + c0 + tc);
    tile[row][tc] = v[0]; tile[row][tc + 1] = v[1];
    tile[row][tc + 2] = v[2]; tile[row][tc + 3] = v[3];
  }
  __syncthreads();
#pragma unroll
  for (int j = 0; j < 4; ++j) {
    int row = tr + j * 16;
    bf16x4 v;
    v[0] = tile[tc + 0][row]; v[1] = tile[tc + 1][row];
    v[2] = tile[tc + 2][row]; v[3] = tile[tc + 3][row];
    *(bf16x4*)(dst + (long)(c0 + row) * R + r0 + tc) = v;
  }
}

// ---- main GEMM: C = A(MxK) * Bt(NxK)^T + bias, 128x128 tile, BK=64 -------
// PIPE 0: single-stage reg-staged LDS (32 KB) -> relies on multi-block/CU
//         overlap; use for grids >= 2 blocks/CU (QKV, FF1).
// PIPE 1: 4-stage global_load_lds pipeline, prefetch depth 3, counted vmcnt
//         (128 KB LDS, 1 block/CU) -> for grids with 1 block/CU (proj, FF2)
//         where there is no inter-block overlap to hide memory time.
// All variants: XCD-aware bijective block swizzle (nwg % 8 == 0 for all our
// grids) so the 6 n-tiles sharing an A-strip land on one XCD's L2.
// EP 0: out = bf16(acc + bias)          (QKV; z batches over 3 weight sets)
// EP 1: out = bf16(gelu(acc + bias))    (FF1)
// EP 2: tmp = acc + bias + resf         (attn-out proj / FF2, f32 out)
template <int EP, int PIPE>
__global__ __launch_bounds__(256) void gemm_kernel(
    const bf16_t* __restrict__ A, const bf16_t* __restrict__ Bt, long btStride,
    const float* b0, const float* b1, const float* b2,
    bf16_t* __restrict__ out, long outStride, const float* __restrict__ resf,
    float* __restrict__ tmp, int M, int N, int K) {
  int z = blockIdx.z;
  Bt += (long)z * btStride;
  const float* bias = (z == 0) ? b0 : (z == 1 ? b1 : b2);
  out += (long)z * outStride;

  // XCD-aware bijective swizzle (requires nwg % 8 == 0; holds: 192/768)
  int nwg = gridDim.x * gridDim.y;
  int bid = blockIdx.y * gridDim.x + blockIdx.x;
  int swz = (bid & 7) * (nwg >> 3) + (bid >> 3);
  int bx = swz % gridDim.x;
  int by = swz / gridDim.x;

  int tid = threadIdx.x;
  int lane = tid & 63;
  int wave = tid >> 6;
  int wm = (wave >> 1) * 64;
  int wn = (wave & 1) * 64;
  int l15 = lane & 15;
  int g4 = lane >> 4;
  int m0 = by * 128;
  int n0 = bx * 128;

  f32x4 acc[4][4] = {};

  if constexpr (PIPE == 0) {
    // layout: [k-octet g(0..7)][row(0..127)] x 8 contiguous bf16
    __shared__ __align__(16) bf16_t As[128 * 64];
    __shared__ __align__(16) bf16_t Bs[128 * 64];
    for (int kt = 0; kt < K; kt += 64) {
      bf16x8 avr[4], bvr[4];
#pragma unroll
      for (int c = 0; c < 4; ++c) {
        int Li = c * 256 + tid;
        int gg = Li >> 7, row = Li & 127;
        avr[c] = *(const bf16x8*)(A + (long)(m0 + row) * K + kt + gg * 8);
        bvr[c] = *(const bf16x8*)(Bt + (long)(n0 + row) * K + kt + gg * 8);
      }
      __syncthreads();  // previous iteration's LDS reads complete
#pragma unroll
      for (int c = 0; c < 4; ++c) {
        int Li = c * 256 + tid;
        *(bf16x8*)(As + Li * 8) = avr[c];
        *(bf16x8*)(Bs + Li * 8) = bvr[c];
      }
      __syncthreads();  // stores visible
#pragma unroll
      for (int ks = 0; ks < 2; ++ks) {
        bf16x8 af[4], bfr[4];
#pragma unroll
        for (int mt = 0; mt < 4; ++mt)
          af[mt] = *(const bf16x8*)(As + (((ks * 4 + g4) * 128) + wm + mt * 16 + l15) * 8);
#pragma unroll
        for (int nt = 0; nt < 4; ++nt)
          bfr[nt] = *(const bf16x8*)(Bs + (((ks * 4 + g4) * 128) + wn + nt * 16 + l15) * 8);
#pragma unroll
        for (int mt = 0; mt < 4; ++mt)
#pragma unroll
          for (int nt = 0; nt < 4; ++nt)
            acc[mt][nt] = __builtin_amdgcn_mfma_f32_16x16x32_bf16(
                af[mt], bfr[nt], acc[mt][nt], 0, 0, 0);
      }
    }
  } else {
    // 4-stage pipeline, prefetch depth 3. LDS dest linear; per-lane source.
    __shared__ __align__(16) bf16_t As[4][128 * 64];
    __shared__ __align__(16) bf16_t Bs[4][128 * 64];
    auto stage = [&](int buf, int kt) {
#pragma unroll
      for (int c = 0; c < 4; ++c) {
        int L0 = c * 256 + wave * 64;   // wave-uniform LDS base (16B units)
        int row = (L0 & 127) + lane;    // lane's source row
        int gg = L0 >> 7;               // k-octet for this issue
        gload_lds16(A + (long)(m0 + row) * K + kt + gg * 8, As[buf] + L0 * 8);
        gload_lds16(Bt + (long)(n0 + row) * K + kt + gg * 8, Bs[buf] + L0 * 8);
      }
    };
    int nk = K >> 6;  // callers guarantee nk >= 4
    stage(0, 0);
    stage(1, 64);
    stage(2, 128);
    for (int it = 0; it < nk; ++it) {
      if (it + 3 < nk) stage((it + 3) & 3, (it + 3) << 6);
      int rem = nk - 1 - it;  // tiles still in flight beyond current
      if (rem >= 3)
        asm volatile("s_waitcnt vmcnt(24)" ::: "memory");
      else if (rem == 2)
        asm volatile("s_waitcnt vmcnt(16)" ::: "memory");
      else if (rem == 1)
        asm volatile("s_waitcnt vmcnt(8)" ::: "memory");
      else
        asm volatile("s_waitcnt vmcnt(0)" ::: "memory");
      __builtin_amdgcn_s_barrier();
      __builtin_amdgcn_sched_barrier(0);  // ds_read strictly after barrier
      int buf = it & 3;
#pragma unroll
      for (int ks = 0; ks < 2; ++ks) {
        bf16x8 af[4], bfr[4];
#pragma unroll
        for (int mt = 0; mt < 4; ++mt)
          af[mt] = *(const bf16x8*)(As[buf] +
                                    (((ks * 4 + g4) * 128) + wm + mt * 16 + l15) * 8);
#pragma unroll
        for (int nt = 0; nt < 4; ++nt)
          bfr[nt] = *(const bf16x8*)(Bs[buf] +
                                     (((ks * 4 + g4) * 128) + wn + nt * 16 + l15) * 8);
#pragma unroll
        for (int mt = 0; mt < 4; ++mt)
#pragma unroll
          for (int nt = 0; nt < 4; ++nt)
            acc[mt][nt] = __builtin_amdgcn_mfma_f32_16x16x32_bf16(
                af[mt], bfr[nt], acc[mt][nt], 0, 0, 0);
      }
      __builtin_amdgcn_sched_barrier(0);  // ds_read strictly before barrier
      __builtin_amdgcn_s_barrier();       // all waves done reading buf
    }
  }

#pragma unroll
  for (int mt = 0; mt < 4; ++mt)
#pragma unroll
    for (int nt = 0; nt < 4; ++nt) {
      int col = n0 + wn + nt * 16 + l15;
      float bval = bias[col];
#pragma unroll
      for (int r = 0; r < 4; ++r) {
        int row = m0 + wm + mt * 16 + g4 * 4 + r;
        float v = acc[mt][nt][r] + bval;
        if (EP == 0) {
          out[(long)row * N + col] = (bf16_t)v;
        } else if (EP == 1) {
          float ge = 0.5f * v * (1.0f + erff(v * 0.70710678118654752f));
          out[(long)row * N + col] = (bf16_t)ge;
        } else {
          tmp[(long)row * N + col] = v + resf[(long)row * N + col];
        }
      }
    }
}

// ---- sliding-window flash attention --------------------------------------
// grid (S/64, H), block 64 (1 wave). q,k: (S,768) bf16; vt: (768,S) bf16.
#define NEGM 30000.0f
__global__ __launch_bounds__(64) void attn_kernel(
    const bf16_t* __restrict__ q, const bf16_t* __restrict__ k,
    const bf16_t* __restrict__ vt, bf16_t* __restrict__ outb) {
  int qt = blockIdx.x * 64;
  int hcol = blockIdx.y * 64;
  int lane = threadIdx.x;
  int l15 = lane & 15, g4 = lane >> 4;
  __shared__ __align__(16) float sbuf[64];

  // Q fragments (B-operand of St = K @ Q^T), scale 1/8 folded in (exact).
  bf16x8 qf[4][2];
#pragma unroll
  for (int nt = 0; nt < 4; ++nt)
#pragma unroll
    for (int ks = 0; ks < 2; ++ks) {
      bf16x8 t = *(const bf16x8*)(q + (long)(qt + nt * 16 + l15) * DMODEL +
                                  hcol + ks * 32 + g4 * 8);
#pragma unroll
      for (int i = 0; i < 8; ++i) t[i] = (bf16_t)((float)t[i] * 0.125f);
      qf[nt][ks] = t;
    }

  f32x4 o[4][4] = {};   // [qmt][dt]; lane r -> O[q=16qmt+4g4+r][d=16dt+l15]
  float mS[4], lS[4];
#pragma unroll
  for (int nt = 0; nt < 4; ++nt) { mS[nt] = -NEGM; lS[nt] = 0.f; }

  int kstart = qt - 256; if (kstart < 0) kstart = 0;
  int kend = qt + 320; if (kend > S_LEN) kend = S_LEN;

  for (int kb = kstart; kb < kend; kb += 64) {
    // St = K_chunk @ Q^T -> St[key=16kt+4g4+r][q=16nt+l15]
    bf16x8 kf[4][2];
#pragma unroll
    for (int kt = 0; kt < 4; ++kt)
#pragma unroll
      for (int ks = 0; ks < 2; ++ks)
        kf[kt][ks] = *(const bf16x8*)(k + (long)(kb + kt * 16 + l15) * DMODEL +
                                      hcol + ks * 32 + g4 * 8);
    f32x4 st[4][4] = {};
#pragma unroll
    for (int kt = 0; kt < 4; ++kt)
#pragma unroll
      for (int nt = 0; nt < 4; ++nt) {
        st[kt][nt] = __builtin_amdgcn_mfma_f32_16x16x32_bf16(
            kf[kt][0], qf[nt][0], st[kt][nt], 0, 0, 0);
        st[kt][nt] = __builtin_amdgcn_mfma_f32_16x16x32_bf16(
            kf[kt][1], qf[nt][1], st[kt][nt], 0, 0, 0);
      }
    // band mask + online softmax stats (per query q = 16nt + l15)
    float alpha[4];
#pragma unroll
    for (int nt = 0; nt < 4; ++nt) {
      int qg = qt + nt * 16 + l15;
      float mx = -NEGM;
#pragma unroll
      for (int kt = 0; kt < 4; ++kt)
#pragma unroll
        for (int r = 0; r < 4; ++r) {
          int kg = kb + kt * 16 + g4 * 4 + r;
          bool valid = (kg >= qg - 256) && (kg <= qg + 256);
          float s = valid ? st[kt][nt][r] : -NEGM;
          st[kt][nt][r] = s;
          mx = fmaxf(mx, s);
        }
      mx = fmaxf(mx, __shfl_xor(mx, 16, 64));
      mx = fmaxf(mx, __shfl_xor(mx, 32, 64));
      float mnew = fmaxf(mS[nt], mx);
      alpha[nt] = exp2f((mS[nt] - mnew) * 1.44269504088896f);
      float ls = 0.f;
#pragma unroll
      for (int kt = 0; kt < 4; ++kt)
#pragma unroll
        for (int r = 0; r < 4; ++r) {
          float p = exp2f((st[kt][nt][r] - mnew) * 1.44269504088896f);
          st[kt][nt][r] = p;
          ls += p;
        }
      ls += __shfl_xor(ls, 16, 64);
      ls += __shfl_xor(ls, 32, 64);
      lS[nt] = lS[nt] * alpha[nt] + ls;
      mS[nt] = mnew;
    }
    // broadcast alpha into O-layout
    if (g4 == 0) {
#pragma unroll
      for (int nt = 0; nt < 4; ++nt) sbuf[nt * 16 + l15] = alpha[nt];
    }
    __syncthreads();
    f32x4 av[4];
#pragma unroll
    for (int qmt = 0; qmt < 4; ++qmt)
      av[qmt] = *(const f32x4*)(sbuf + qmt * 16 + g4 * 4);
#pragma unroll
    for (int qmt = 0; qmt < 4; ++qmt)
#pragma unroll
      for (int dt = 0; dt < 4; ++dt)
#pragma unroll
        for (int r = 0; r < 4; ++r) o[qmt][dt][r] *= av[qmt][r];
    // PV: St lanes are already exactly the A-operand of 16x16x16 MFMA.
#pragma unroll
    for (int kt = 0; kt < 4; ++kt) {
      bf16x4 pa[4];
#pragma unroll
      for (int qmt = 0; qmt < 4; ++qmt)
#pragma unroll
        for (int i = 0; i < 4; ++i) pa[qmt][i] = (bf16_t)st[kt][qmt][i];
      bf16x4 vf[4];
#pragma unroll
      for (int dt = 0; dt < 4; ++dt)
        vf[dt] = *(const bf16x4*)(vt + (long)(hcol + dt * 16 + l15) * S_LEN +
                                  kb + kt * 16 + g4 * 4);
#pragma unroll
      for (int qmt = 0; qmt < 4; ++qmt)
#pragma unroll
        for (int dt = 0; dt < 4; ++dt)
          o[qmt][dt] = mfma16x16x16(pa[qmt], vf[dt], o[qmt][dt]);
    }
    __syncthreads();
  }
  // final normalize by l
  if (g4 == 0) {
#pragma unroll
    for (int nt = 0; nt < 4; ++nt) sbuf[nt * 16 + l15] = lS[nt];
  }
  __syncthreads();
  f32x4 lv[4];
#pragma unroll
  for (int qmt = 0; qmt < 4; ++qmt)
    lv[qmt] = *(const f32x4*)(sbuf + qmt * 16 + g4 * 4);
#pragma unroll
  for (int qmt = 0; qmt < 4; ++qmt)
#pragma unroll
    for (int dt = 0; dt < 4; ++dt)
#pragma unroll
      for (int r = 0; r < 4; ++r)
        outb[(long)(qt + qmt * 16 + g4 * 4 + r) * DMODEL + hcol + dt * 16 +
             l15] = (bf16_t)(o[qmt][dt][r] / lv[qmt][r]);
}

// ---- classifier heads (f32 weights, f32 out) ------------------------------
__global__ __launch_bounds__(256) void cls_kernel(
    const float* __restrict__ xf, const float* cW1, const float* cb1,
    const float* cW2, const float* cb2, const float* dW1,
    const float* db1, const float* dW2, const float* db2,
    float* __restrict__ out) {
  __shared__ float pooled[768];
  __shared__ float hbuf[512];
  int t = threadIdx.x;
  bool dec = (blockIdx.x == 1);
  const float* W1 = dec ? dW1 : cW1;
  const float* B1 = dec ? db1 : cb1;
  const float* W2 = dec ? dW2 : cW2;
  const float* B2 = dec ? db2 : cb2;
  int nout = dec ? 10 : 5;
  float* op = out + (dec ? 5 : 0);
#pragma unroll
  for (int j = 0; j < 3; ++j) pooled[t + j * 256] = xf[t + j * 256];
  __syncthreads();
  for (int n = t; n < 512; n += 256) {
    float a = B1[n];
    for (int k2 = 0; k2 < 768; ++k2)
      a += pooled[k2] * W1[(long)k2 * 512 + n];
    hbuf[n] = fmaxf(a, 0.f);
  }
  __syncthreads();
  if (t < nout) {
    float a = B2[t];
    for (int i = 0; i < 512; ++i) a += hbuf[i] * W2[i * nout + t];
    op[t] = a;
  }
}

// ---- host orchestration --------------------------------------------------
extern "C" void kernel_launch(void* const* d_in, const int* in_sizes, int n_in,
                              void* d_out, int out_size, void* d_ws,
                              size_t ws_size, hipStream_t stream) {
  const int* ids = (const int*)d_in[0];
  const int* amask = (const int*)d_in[1];
  const float* emb_word = (const float*)d_in[2];
  const float* emb_pos = (const float*)d_in[3];
  const float* emb_type = (const float*)d_in[4];
  const float* emb_g = (const float*)d_in[5];
  const float* emb_b = (const float*)d_in[6];
  const float* Wq = (const float*)d_in[7];
  const float* bq = (const float*)d_in[8];
  const float* Wk = (const float*)d_in[9];
  const float* bk = (const float*)d_in[10];
  const float* Wv = (const float*)d_in[11];
  const float* bv = (const float*)d_in[12];
  const float* Wo = (const float*)d_in[13];
  const float* bo = (const float*)d_in[14];
  const float* ln1g = (const float*)d_in[15];
  const float* ln1b = (const float*)d_in[16];
  const float* W1 = (const float*)d_in[17];
  const float* b1 = (const float*)d_in[18];
  const float* W2 = (const float*)d_in[19];
  const float* b2 = (const float*)d_in[20];
  const float* ln2g = (const float*)d_in[21];
  const float* ln2b = (const float*)d_in[22];
  const float* cW1 = (const float*)d_in[23];
  const float* cb1 = (const float*)d_in[24];
  const float* cW2 = (const float*)d_in[25];
  const float* cb2 = (const float*)d_in[26];
  const float* dW1 = (const float*)d_in[27];
  const float* db1 = (const float*)d_in[28];
  const float* dW2 = (const float*)d_in[29];
  const float* db2 = (const float*)d_in[30];
  float* outp = (float*)d_out;

  const size_t SD = (size_t)S_LEN * DMODEL;
  const size_t DD = (size_t)DMODEL * DMODEL;
  const size_t DF = (size_t)DMODEL * FFDIM;
  const size_t SF = (size_t)S_LEN * FFDIM;

  char* p = (char*)d_ws;
  auto carve = [&](size_t bytes) {
    char* r = p;
    p += (bytes + 255) & ~(size_t)255;
    return (void*)r;
  };

  size_t actsBytes = SD * 2 + SD * 4 + 3 * SD * 2 + SD * 2 + SD * 2 + SF * 2 +
                     SD * 4 + S_LEN * 4 + 16 * 256;
  size_t fullW = (36 * DD + 12 * DD + 24 * DF) * 2 + 16 * 256;
  bool full = ws_size >= actsBytes + fullW;

  bf16_t *qkvt, *wot, *w1t, *w2t;
  if (full) {
    qkvt = (bf16_t*)carve(36 * DD * 2);
    wot = (bf16_t*)carve(12 * DD * 2);
    w1t = (bf16_t*)carve(12 * DF * 2);
    w2t = (bf16_t*)carve(12 * DF * 2);
  } else {
    qkvt = (bf16_t*)carve(3 * DD * 2);
    wot = (bf16_t*)carve(DD * 2);
    w1t = (bf16_t*)carve(DF * 2);
    w2t = (bf16_t*)carve(DF * 2);
  }
  bf16_t* xb = (bf16_t*)carve(SD * 2);
  float* xf = (float*)carve(SD * 4);
  bf16_t* qkv = (bf16_t*)carve(3 * SD * 2);
  bf16_t* vt = (bf16_t*)carve(SD * 2);
  bf16_t* attnb = (bf16_t*)carve(SD * 2);
  bf16_t* hbuf = (bf16_t*)carve(SF * 2);
  float* tmp = (float*)carve(SD * 4);
  int* pids = (int*)carve(S_LEN * 4);

  posid_kernel<<<1, 256, 0, stream>>>(amask, pids);
  embed_kernel<<<S_LEN, 256, 0, stream>>>(ids, pids, emb_word, emb_pos,
                                          emb_type, emb_g, emb_b, xf, xb);

  if (full) {
    trc_kernel<<<dim3(12, 12, 12), 256, 0, stream>>>(Wq, qkvt, 768, 768, DD, 3 * DD);
    trc_kernel<<<dim3(12, 12, 12), 256, 0, stream>>>(Wk, qkvt + DD, 768, 768, DD, 3 * DD);
    trc_kernel<<<dim3(12, 12, 12), 256, 0, stream>>>(Wv, qkvt + 2 * DD, 768, 768, DD, 3 * DD);
    trc_kernel<<<dim3(12, 12, 12), 256, 0, stream>>>(Wo, wot, 768, 768, DD, DD);
    trc_kernel<<<dim3(48, 12, 12), 256, 0, stream>>>(W1, w1t, 768, 3072, DF, DF);
    trc_kernel<<<dim3(12, 48, 12), 256, 0, stream>>>(W2, w2t, 3072, 768, DF, DF);
  }

  for (int i = 0; i < NLAYER; ++i) {
    const bf16_t *qkvt_i, *wot_i, *w1t_i, *w2t_i;
    if (full) {
      qkvt_i = qkvt + (size_t)i * 3 * DD;
      wot_i = wot + (size_t)i * DD;
      w1t_i = w1t + (size_t)i * DF;
      w2t_i = w2t + (size_t)i * DF;
    } else {
      trc_kernel<<<dim3(12, 12, 1), 256, 0, stream>>>(Wq + (size_t)i * DD, qkvt, 768, 768, 0, 0);
      trc_kernel<<<dim3(12, 12, 1), 256, 0, stream>>>(Wk + (size_t)i * DD, qkvt + DD, 768, 768, 0, 0);
      trc_kernel<<<dim3(12, 12, 1), 256, 0, stream>>>(Wv + (size_t)i * DD, qkvt + 2 * DD, 768, 768, 0, 0);
      trc_kernel<<<dim3(12, 12, 1), 256, 0, stream>>>(Wo + (size_t)i * DD, wot, 768, 768, 0, 0);
      trc_kernel<<<dim3(48, 12, 1), 256, 0, stream>>>(W1 + (size_t)i * DF, w1t, 768, 3072, 0, 0);
      trc_kernel<<<dim3(12, 48, 1), 256, 0, stream>>>(W2 + (size_t)i * DF, w2t, 3072, 768, 0, 0);
      qkvt_i = qkvt; wot_i = wot; w1t_i = w1t; w2t_i = w2t;
    }
    gemm_kernel<0, 0><<<dim3(6, 32, 3), 256, 0, stream>>>(
        xb, qkvt_i, (long)DD, bq + i * 768, bk + i * 768, bv + i * 768, qkv,
        (long)SD, nullptr, nullptr, S_LEN, 768, 768);
    tr_kernel<<<dim3(12, 64, 1), 256, 0, stream>>>(qkv + 2 * SD, vt, 4096, 768);
    attn_kernel<<<dim3(64, 12), 64, 0, stream>>>(qkv, qkv + SD, vt, attnb);
    gemm_kernel<2, 1><<<dim3(6, 32, 1), 256, 0, stream>>>(
        attnb, wot_i, 0, bo + i * 768, nullptr, nullptr, nullptr, 0, xf, tmp,
        S_LEN, 768, 768);
    ln_kernel<<<S_LEN, 256, 0, stream>>>(tmp, ln1g + i * 768, ln1b + i * 768, xf, xb);
    gemm_kernel<1, 0><<<dim3(24, 32, 1), 256, 0, stream>>>(
        xb, w1t_i, 0, b1 + (size_t)i * FFDIM, nullptr, nullptr, hbuf, 0,
        nullptr, nullptr, S_LEN, FFDIM, 768);
    gemm_kernel<2, 1><<<dim3(6, 32, 1), 256, 0, stream>>>(
        hbuf, w2t_i, 0, b2 + i * 768, nullptr, nullptr, nullptr, 0, xf, tmp,
        S_LEN, 768, FFDIM);
    ln_kernel<<<S_LEN, 256, 0, stream>>>(tmp, ln2g + i * 768, ln2b + i * 768, xf, xb);
  }
  cls_kernel<<<2, 256, 0, stream>>>(xf, cW1, cb1, cW2, cb2, dW1, db1, dW2, db2, outp);
}

// Round 3
// 3747.884 us; speedup vs baseline: 1.1345x; 1.0909x over previous
//
#include <hip/hip_runtime.h>
#include <hip/hip_bf16.h>
#include <math.h>

typedef __bf16 bf16_t;
typedef __bf16 bf16x8 __attribute__((ext_vector_type(8)));
typedef __bf16 bf16x4 __attribute__((ext_vector_type(4)));
typedef float  f32x4  __attribute__((ext_vector_type(4)));
typedef short  s16x4  __attribute__((ext_vector_type(4)));

#define S_LEN 4096
#define DMODEL 768
#define NHEAD 12
#define NLAYER 12
#define FFDIM 3072

// ---- MFMA helpers -------------------------------------------------------
static __device__ inline f32x4 mfma16x16x16(bf16x4 a, bf16x4 b, f32x4 c) {
#if __has_builtin(__builtin_amdgcn_mfma_f32_16x16x16_bf16)
  return __builtin_amdgcn_mfma_f32_16x16x16_bf16(a, b, c, 0, 0, 0);
#else
  return __builtin_amdgcn_mfma_f32_16x16x16bf16_1k(
      __builtin_bit_cast(s16x4, a), __builtin_bit_cast(s16x4, b), c, 0, 0, 0);
#endif
}

// async global -> LDS, 16B per lane. LDS dest is wave-uniform base + lane*16.
static __device__ inline void gload_lds16(const void* g, void* l) {
  __builtin_amdgcn_global_load_lds(
      (const __attribute__((address_space(1))) void*)g,
      (__attribute__((address_space(3))) void*)l, 16, 0, 0);
}

// ---- pos_ids = cumsum(mask)*mask + 1 (B=1, S=4096) ----------------------
__global__ __launch_bounds__(256) void posid_kernel(const int* __restrict__ m,
                                                    int* __restrict__ pids) {
  __shared__ int ps[256];
  int t = threadIdx.x;
  int base = t * 16;
  int loc[16], mv[16];
  int s = 0;
#pragma unroll
  for (int j = 0; j < 16; ++j) { mv[j] = m[base + j]; s += mv[j]; loc[j] = s; }
  ps[t] = s;
  __syncthreads();
  for (int off = 1; off < 256; off <<= 1) {
    int v = (t >= off) ? ps[t - off] : 0;
    __syncthreads();
    ps[t] += v;
    __syncthreads();
  }
  int pre = t ? ps[t - 1] : 0;
#pragma unroll
  for (int j = 0; j < 16; ++j) pids[base + j] = (pre + loc[j]) * mv[j] + 1;
}

// ---- block reduction helper (256 threads) -------------------------------
__device__ inline float blk_sum(float v, float* sred) {
#pragma unroll
  for (int o = 32; o; o >>= 1) v += __shfl_down(v, o, 64);
  int w = threadIdx.x >> 6;
  __syncthreads();
  if ((threadIdx.x & 63) == 0) sred[w] = v;
  __syncthreads();
  return sred[0] + sred[1] + sred[2] + sred[3];
}

// ---- embedding gather + LN (f32 inputs) ----------------------------------
__global__ __launch_bounds__(256) void embed_kernel(
    const int* __restrict__ ids, const int* __restrict__ pids,
    const float* __restrict__ ew, const float* __restrict__ ep,
    const float* __restrict__ et, const float* __restrict__ g,
    const float* __restrict__ b, float* __restrict__ xf,
    bf16_t* __restrict__ xb) {
  __shared__ float sred[4];
  int s = blockIdx.x, t = threadIdx.x;
  long wb = (long)ids[s] * DMODEL;
  long pb = (long)pids[s] * DMODEL;
  float v[3];
#pragma unroll
  for (int j = 0; j < 3; ++j) {
    int d = t + j * 256;
    v[j] = ew[wb + d] + ep[pb + d] + et[d];
  }
  float mu = blk_sum(v[0] + v[1] + v[2], sred) * (1.0f / 768.0f);
  float ss = 0.f;
#pragma unroll
  for (int j = 0; j < 3; ++j) { v[j] -= mu; ss += v[j] * v[j]; }
  float rs = rsqrtf(blk_sum(ss, sred) * (1.0f / 768.0f) + 1e-5f);
#pragma unroll
  for (int j = 0; j < 3; ++j) {
    int d = t + j * 256;
    float o = v[j] * rs * g[d] + b[d];
    xf[(long)s * DMODEL + d] = o;
    xb[(long)s * DMODEL + d] = (bf16_t)o;
  }
}

// ---- LN over f32 tmp -> xf (f32 master) + xb (bf16 mirror) ---------------
__global__ __launch_bounds__(256) void ln_kernel(
    const float* __restrict__ in, const float* __restrict__ g,
    const float* __restrict__ b, float* __restrict__ xf,
    bf16_t* __restrict__ xb) {
  __shared__ float sred[4];
  int row = blockIdx.x, t = threadIdx.x;
  const float* r = in + (long)row * DMODEL;
  float v[3] = {r[t], r[t + 256], r[t + 512]};
  float mu = blk_sum(v[0] + v[1] + v[2], sred) * (1.0f / 768.0f);
  float ss = 0.f;
#pragma unroll
  for (int j = 0; j < 3; ++j) { v[j] -= mu; ss += v[j] * v[j]; }
  float rs = rsqrtf(blk_sum(ss, sred) * (1.0f / 768.0f) + 1e-5f);
#pragma unroll
  for (int j = 0; j < 3; ++j) {
    int d = t + j * 256;
    float o = v[j] * rs * g[d] + b[d];
    xf[(long)row * DMODEL + d] = o;
    xb[(long)row * DMODEL + d] = (bf16_t)o;
  }
}

// ---- LN over (sum of ns split-K partials + gemm bias + residual xf) ------
// val[d] = sum_z pt[z][row][d] + gb[d] + xf[row][d]; then LN -> xf, xb.
__global__ __launch_bounds__(256) void lnred_kernel(
    const float* __restrict__ pt, int ns, const float* __restrict__ gb,
    const float* __restrict__ g, const float* __restrict__ b,
    float* __restrict__ xf, bf16_t* __restrict__ xb) {
  __shared__ float sred[4];
  const long MN = (long)S_LEN * DMODEL;
  int row = blockIdx.x, t = threadIdx.x;
  long rb = (long)row * DMODEL;
  float v[3];
#pragma unroll
  for (int j = 0; j < 3; ++j) {
    int d = t + j * 256;
    float a = gb[d] + xf[rb + d];
    for (int z = 0; z < ns; ++z) a += pt[(long)z * MN + rb + d];
    v[j] = a;
  }
  float mu = blk_sum(v[0] + v[1] + v[2], sred) * (1.0f / 768.0f);
  float ss = 0.f;
#pragma unroll
  for (int j = 0; j < 3; ++j) { v[j] -= mu; ss += v[j] * v[j]; }
  float rs = rsqrtf(blk_sum(ss, sred) * (1.0f / 768.0f) + 1e-5f);
#pragma unroll
  for (int j = 0; j < 3; ++j) {
    int d = t + j * 256;
    float o = v[j] * rs * g[d] + b[d];
    xf[rb + d] = o;
    xb[rb + d] = (bf16_t)o;
  }
}

// ---- f32 -> bf16 transpose (weights), 64x64 tiles ------------------------
__global__ __launch_bounds__(256) void trc_kernel(const float* __restrict__ src,
                                                  bf16_t* __restrict__ dst,
                                                  int R, int C, long srcStride,
                                                  long dstStride) {
  src += (long)blockIdx.z * srcStride;
  dst += (long)blockIdx.z * dstStride;
  __shared__ float tile[64][65];
  int r0 = blockIdx.y * 64, c0 = blockIdx.x * 64;
  int t = threadIdx.x;
  int tr = t >> 4;
  int tc = (t & 15) * 4;
#pragma unroll
  for (int j = 0; j < 4; ++j) {
    int row = tr + j * 16;
    float4 v = *(const float4*)(src + (long)(r0 + row) * C + c0 + tc);
    tile[row][tc] = v.x; tile[row][tc + 1] = v.y;
    tile[row][tc + 2] = v.z; tile[row][tc + 3] = v.w;
  }
  __syncthreads();
#pragma unroll
  for (int j = 0; j < 4; ++j) {
    int row = tr + j * 16;  // dst row within tile (= src col)
    bf16x4 v;
    v[0] = (bf16_t)tile[tc + 0][row]; v[1] = (bf16_t)tile[tc + 1][row];
    v[2] = (bf16_t)tile[tc + 2][row]; v[3] = (bf16_t)tile[tc + 3][row];
    *(bf16x4*)(dst + (long)(c0 + row) * R + r0 + tc) = v;
  }
}

// ---- bf16 -> bf16 transpose (V), 64x64 tiles ------------------------------
__global__ __launch_bounds__(256) void tr_kernel(const bf16_t* __restrict__ src,
                                                 bf16_t* __restrict__ dst,
                                                 int R, int C) {
  __shared__ bf16_t tile[64][68];
  int r0 = blockIdx.y * 64, c0 = blockIdx.x * 64;
  int t = threadIdx.x;
  int tr = t >> 4;
  int tc = (t & 15) * 4;
#pragma unroll
  for (int j = 0; j < 4; ++j) {
    int row = tr + j * 16;
    bf16x4 v = *(const bf16x4*)(src + (long)(r0 + row) * C + c0 + tc);
    tile[row][tc] = v[0]; tile[row][tc + 1] = v[1];
    tile[row][tc + 2] = v[2]; tile[row][tc + 3] = v[3];
  }
  __syncthreads();
#pragma unroll
  for (int j = 0; j < 4; ++j) {
    int row = tr + j * 16;
    bf16x4 v;
    v[0] = tile[tc + 0][row]; v[1] = tile[tc + 1][row];
    v[2] = tile[tc + 2][row]; v[3] = tile[tc + 3][row];
    *(bf16x4*)(dst + (long)(c0 + row) * R + r0 + tc) = v;
  }
}

// ---- main GEMM: C = A(MxK) * Bt(NxK)^T + bias, 128x128 tile, BK=64 -------
// m97 structure: single 32 KB LDS buffer, global_load_lds width-16 staging,
// 2 barriers per K-step. Relies on >=2 co-resident blocks/CU for overlap
// (32 KB LDS -> up to 5 blocks/CU). Split-K (EP 3) raises small grids to
// 3 blocks/CU. XCD-aware bijective block swizzle (all grids have nwg%8==0).
// EP 0: out = bf16(acc + bias); z = weight set      (QKV)
// EP 1: out = bf16(gelu(acc + bias))                (FF1)
// EP 2: tmp = acc + bias + resf (f32)               (fallback proj/FF2)
// EP 3: tmp[z] = acc (f32 partial); z = K-chunk     (split-K proj/FF2)
template <int EP>
__global__ __launch_bounds__(256) void gemm_kernel(
    const bf16_t* __restrict__ A, const bf16_t* __restrict__ Bt, long btStride,
    const float* b0, const float* b1, const float* b2,
    bf16_t* __restrict__ out, long outStride, const float* __restrict__ resf,
    float* __restrict__ tmp, int M, int N, int K, int kc) {
  int z = blockIdx.z;
  const float* bias = nullptr;
  int kBeg = 0;
  if constexpr (EP == 3) {
    kBeg = z * kc;  // K-chunk
  } else {
    Bt += (long)z * btStride;
    bias = (z == 0) ? b0 : (z == 1 ? b1 : b2);
    out += (long)z * outStride;
  }

  // XCD-aware bijective swizzle (requires nwg % 8 == 0; holds: 192/768)
  int nwg = gridDim.x * gridDim.y;
  int bid = blockIdx.y * gridDim.x + blockIdx.x;
  int swz = (bid & 7) * (nwg >> 3) + (bid >> 3);
  int bx = swz % gridDim.x;
  int by = swz / gridDim.x;

  int tid = threadIdx.x;
  int lane = tid & 63;
  int wave = tid >> 6;
  int wm = (wave >> 1) * 64;
  int wn = (wave & 1) * 64;
  int l15 = lane & 15;
  int g4 = lane >> 4;
  int m0 = by * 128;
  int n0 = bx * 128;

  f32x4 acc[4][4] = {};

  // layout: [k-octet g(0..7)][row(0..127)] x 8 contiguous bf16
  __shared__ __align__(16) bf16_t As[128 * 64];
  __shared__ __align__(16) bf16_t Bs[128 * 64];

  for (int kt = kBeg; kt < kBeg + kc; kt += 64) {
    // stage: 8 x 1KB global_load_lds per wave (A and B tiles)
#pragma unroll
    for (int c = 0; c < 4; ++c) {
      int L0 = c * 256 + wave * 64;   // wave-uniform LDS base (16B units)
      int row = (L0 & 127) + lane;    // lane's source row
      int gg = L0 >> 7;               // k-octet for this issue
      gload_lds16(A + (long)(m0 + row) * K + kt + gg * 8, As + L0 * 8);
      gload_lds16(Bt + (long)(n0 + row) * K + kt + gg * 8, Bs + L0 * 8);
    }
    __syncthreads();  // drains vmcnt(0): staged data visible to all waves
#pragma unroll
    for (int ks = 0; ks < 2; ++ks) {
      bf16x8 af[4], bfr[4];
#pragma unroll
      for (int mt = 0; mt < 4; ++mt)
        af[mt] = *(const bf16x8*)(As + (((ks * 4 + g4) * 128) + wm + mt * 16 + l15) * 8);
#pragma unroll
      for (int nt = 0; nt < 4; ++nt)
        bfr[nt] = *(const bf16x8*)(Bs + (((ks * 4 + g4) * 128) + wn + nt * 16 + l15) * 8);
#pragma unroll
      for (int mt = 0; mt < 4; ++mt)
#pragma unroll
        for (int nt = 0; nt < 4; ++nt)
          acc[mt][nt] = __builtin_amdgcn_mfma_f32_16x16x32_bf16(
              af[mt], bfr[nt], acc[mt][nt], 0, 0, 0);
    }
    __syncthreads();  // all waves done reading As/Bs before next stage
  }

#pragma unroll
  for (int mt = 0; mt < 4; ++mt)
#pragma unroll
    for (int nt = 0; nt < 4; ++nt) {
      int col = n0 + wn + nt * 16 + l15;
      float bval = (EP == 3) ? 0.f : bias[col];
#pragma unroll
      for (int r = 0; r < 4; ++r) {
        int row = m0 + wm + mt * 16 + g4 * 4 + r;
        float v = acc[mt][nt][r] + bval;
        if (EP == 0) {
          out[(long)row * N + col] = (bf16_t)v;
        } else if (EP == 1) {
          float ge = 0.5f * v * (1.0f + erff(v * 0.70710678118654752f));
          out[(long)row * N + col] = (bf16_t)ge;
        } else if (EP == 2) {
          tmp[(long)row * N + col] = v + resf[(long)row * N + col];
        } else {
          tmp[(long)z * ((long)M * N) + (long)row * N + col] = v;
        }
      }
    }
}

// ---- sliding-window flash attention --------------------------------------
// grid (S/64, H), block 64 (1 wave). q,k: (S,768) bf16; vt: (768,S) bf16.
#define NEGM 30000.0f
__global__ __launch_bounds__(64) void attn_kernel(
    const bf16_t* __restrict__ q, const bf16_t* __restrict__ k,
    const bf16_t* __restrict__ vt, bf16_t* __restrict__ outb) {
  int qt = blockIdx.x * 64;
  int hcol = blockIdx.y * 64;
  int lane = threadIdx.x;
  int l15 = lane & 15, g4 = lane >> 4;
  __shared__ __align__(16) float sbuf[64];

  // Q fragments (B-operand of St = K @ Q^T), scale 1/8 folded in (exact).
  bf16x8 qf[4][2];
#pragma unroll
  for (int nt = 0; nt < 4; ++nt)
#pragma unroll
    for (int ks = 0; ks < 2; ++ks) {
      bf16x8 t = *(const bf16x8*)(q + (long)(qt + nt * 16 + l15) * DMODEL +
                                  hcol + ks * 32 + g4 * 8);
#pragma unroll
      for (int i = 0; i < 8; ++i) t[i] = (bf16_t)((float)t[i] * 0.125f);
      qf[nt][ks] = t;
    }

  f32x4 o[4][4] = {};   // [qmt][dt]; lane r -> O[q=16qmt+4g4+r][d=16dt+l15]
  float mS[4], lS[4];
#pragma unroll
  for (int nt = 0; nt < 4; ++nt) { mS[nt] = -NEGM; lS[nt] = 0.f; }

  int kstart = qt - 256; if (kstart < 0) kstart = 0;
  int kend = qt + 320; if (kend > S_LEN) kend = S_LEN;

  for (int kb = kstart; kb < kend; kb += 64) {
    // St = K_chunk @ Q^T -> St[key=16kt+4g4+r][q=16nt+l15]
    bf16x8 kf[4][2];
#pragma unroll
    for (int kt = 0; kt < 4; ++kt)
#pragma unroll
      for (int ks = 0; ks < 2; ++ks)
        kf[kt][ks] = *(const bf16x8*)(k + (long)(kb + kt * 16 + l15) * DMODEL +
                                      hcol + ks * 32 + g4 * 8);
    f32x4 st[4][4] = {};
#pragma unroll
    for (int kt = 0; kt < 4; ++kt)
#pragma unroll
      for (int nt = 0; nt < 4; ++nt) {
        st[kt][nt] = __builtin_amdgcn_mfma_f32_16x16x32_bf16(
            kf[kt][0], qf[nt][0], st[kt][nt], 0, 0, 0);
        st[kt][nt] = __builtin_amdgcn_mfma_f32_16x16x32_bf16(
            kf[kt][1], qf[nt][1], st[kt][nt], 0, 0, 0);
      }
    // band mask + online softmax stats (per query q = 16nt + l15)
    float alpha[4];
#pragma unroll
    for (int nt = 0; nt < 4; ++nt) {
      int qg = qt + nt * 16 + l15;
      float mx = -NEGM;
#pragma unroll
      for (int kt = 0; kt < 4; ++kt)
#pragma unroll
        for (int r = 0; r < 4; ++r) {
          int kg = kb + kt * 16 + g4 * 4 + r;
          bool valid = (kg >= qg - 256) && (kg <= qg + 256);
          float s = valid ? st[kt][nt][r] : -NEGM;
          st[kt][nt][r] = s;
          mx = fmaxf(mx, s);
        }
      mx = fmaxf(mx, __shfl_xor(mx, 16, 64));
      mx = fmaxf(mx, __shfl_xor(mx, 32, 64));
      float mnew = fmaxf(mS[nt], mx);
      alpha[nt] = exp2f((mS[nt] - mnew) * 1.44269504088896f);
      float ls = 0.f;
#pragma unroll
      for (int kt = 0; kt < 4; ++kt)
#pragma unroll
        for (int r = 0; r < 4; ++r) {
          float p = exp2f((st[kt][nt][r] - mnew) * 1.44269504088896f);
          st[kt][nt][r] = p;
          ls += p;
        }
      ls += __shfl_xor(ls, 16, 64);
      ls += __shfl_xor(ls, 32, 64);
      lS[nt] = lS[nt] * alpha[nt] + ls;
      mS[nt] = mnew;
    }
    // broadcast alpha into O-layout
    if (g4 == 0) {
#pragma unroll
      for (int nt = 0; nt < 4; ++nt) sbuf[nt * 16 + l15] = alpha[nt];
    }
    __syncthreads();
    f32x4 av[4];
#pragma unroll
    for (int qmt = 0; qmt < 4; ++qmt)
      av[qmt] = *(const f32x4*)(sbuf + qmt * 16 + g4 * 4);
#pragma unroll
    for (int qmt = 0; qmt < 4; ++qmt)
#pragma unroll
      for (int dt = 0; dt < 4; ++dt)
#pragma unroll
        for (int r = 0; r < 4; ++r) o[qmt][dt][r] *= av[qmt][r];
    // PV: St lanes are already exactly the A-operand of 16x16x16 MFMA.
#pragma unroll
    for (int kt = 0; kt < 4; ++kt) {
      bf16x4 pa[4];
#pragma unroll
      for (int qmt = 0; qmt < 4; ++qmt)
#pragma unroll
        for (int i = 0; i < 4; ++i) pa[qmt][i] = (bf16_t)st[kt][qmt][i];
      bf16x4 vf[4];
#pragma unroll
      for (int dt = 0; dt < 4; ++dt)
        vf[dt] = *(const bf16x4*)(vt + (long)(hcol + dt * 16 + l15) * S_LEN +
                                  kb + kt * 16 + g4 * 4);
#pragma unroll
      for (int qmt = 0; qmt < 4; ++qmt)
#pragma unroll
        for (int dt = 0; dt < 4; ++dt)
          o[qmt][dt] = mfma16x16x16(pa[qmt], vf[dt], o[qmt][dt]);
    }
    __syncthreads();
  }
  // final normalize by l
  if (g4 == 0) {
#pragma unroll
    for (int nt = 0; nt < 4; ++nt) sbuf[nt * 16 + l15] = lS[nt];
  }
  __syncthreads();
  f32x4 lv[4];
#pragma unroll
  for (int qmt = 0; qmt < 4; ++qmt)
    lv[qmt] = *(const f32x4*)(sbuf + qmt * 16 + g4 * 4);
#pragma unroll
  for (int qmt = 0; qmt < 4; ++qmt)
#pragma unroll
    for (int dt = 0; dt < 4; ++dt)
#pragma unroll
      for (int r = 0; r < 4; ++r)
        outb[(long)(qt + qmt * 16 + g4 * 4 + r) * DMODEL + hcol + dt * 16 +
             l15] = (bf16_t)(o[qmt][dt][r] / lv[qmt][r]);
}

// ---- classifier heads (f32 weights, f32 out) ------------------------------
__global__ __launch_bounds__(256) void cls_kernel(
    const float* __restrict__ xf, const float* cW1, const float* cb1,
    const float* cW2, const float* cb2, const float* dW1,
    const float* db1, const float* dW2, const float* db2,
    float* __restrict__ out) {
  __shared__ float pooled[768];
  __shared__ float hbuf[512];
  int t = threadIdx.x;
  bool dec = (blockIdx.x == 1);
  const float* W1 = dec ? dW1 : cW1;
  const float* B1 = dec ? db1 : cb1;
  const float* W2 = dec ? dW2 : cW2;
  const float* B2 = dec ? db2 : cb2;
  int nout = dec ? 10 : 5;
  float* op = out + (dec ? 5 : 0);
#pragma unroll
  for (int j = 0; j < 3; ++j) pooled[t + j * 256] = xf[t + j * 256];
  __syncthreads();
  for (int n = t; n < 512; n += 256) {
    float a = B1[n];
    for (int k2 = 0; k2 < 768; ++k2)
      a += pooled[k2] * W1[(long)k2 * 512 + n];
    hbuf[n] = fmaxf(a, 0.f);
  }
  __syncthreads();
  if (t < nout) {
    float a = B2[t];
    for (int i = 0; i < 512; ++i) a += hbuf[i] * W2[i * nout + t];
    op[t] = a;
  }
}

// ---- host orchestration --------------------------------------------------
extern "C" void kernel_launch(void* const* d_in, const int* in_sizes, int n_in,
                              void* d_out, int out_size, void* d_ws,
                              size_t ws_size, hipStream_t stream) {
  const int* ids = (const int*)d_in[0];
  const int* amask = (const int*)d_in[1];
  const float* emb_word = (const float*)d_in[2];
  const float* emb_pos = (const float*)d_in[3];
  const float* emb_type = (const float*)d_in[4];
  const float* emb_g = (const float*)d_in[5];
  const float* emb_b = (const float*)d_in[6];
  const float* Wq = (const float*)d_in[7];
  const float* bq = (const float*)d_in[8];
  const float* Wk = (const float*)d_in[9];
  const float* bk = (const float*)d_in[10];
  const float* Wv = (const float*)d_in[11];
  const float* bv = (const float*)d_in[12];
  const float* Wo = (const float*)d_in[13];
  const float* bo = (const float*)d_in[14];
  const float* ln1g = (const float*)d_in[15];
  const float* ln1b = (const float*)d_in[16];
  const float* W1 = (const float*)d_in[17];
  const float* b1 = (const float*)d_in[18];
  const float* W2 = (const float*)d_in[19];
  const float* b2 = (const float*)d_in[20];
  const float* ln2g = (const float*)d_in[21];
  const float* ln2b = (const float*)d_in[22];
  const float* cW1 = (const float*)d_in[23];
  const float* cb1 = (const float*)d_in[24];
  const float* cW2 = (const float*)d_in[25];
  const float* cb2 = (const float*)d_in[26];
  const float* dW1 = (const float*)d_in[27];
  const float* db1 = (const float*)d_in[28];
  const float* dW2 = (const float*)d_in[29];
  const float* db2 = (const float*)d_in[30];
  float* outp = (float*)d_out;

  const size_t SD = (size_t)S_LEN * DMODEL;
  const size_t DD = (size_t)DMODEL * DMODEL;
  const size_t DF = (size_t)DMODEL * FFDIM;
  const size_t SF = (size_t)S_LEN * FFDIM;

  char* p = (char*)d_ws;
  auto carve = [&](size_t bytes) {
    char* r = p;
    p += (bytes + 255) & ~(size_t)255;
    return (void*)r;
  };

  size_t actsBytes = SD * 2 + SD * 4 + 3 * SD * 2 + SD * 2 + SD * 2 + SF * 2 +
                     SD * 4 + S_LEN * 4 + 16 * 256;
  size_t fullW = (36 * DD + 12 * DD + 24 * DF) * 2 + 16 * 256;
  bool full = ws_size >= actsBytes + fullW;

  bf16_t *qkvt, *wot, *w1t, *w2t;
  if (full) {
    qkvt = (bf16_t*)carve(36 * DD * 2);
    wot = (bf16_t*)carve(12 * DD * 2);
    w1t = (bf16_t*)carve(12 * DF * 2);
    w2t = (bf16_t*)carve(12 * DF * 2);
  } else {
    qkvt = (bf16_t*)carve(3 * DD * 2);
    wot = (bf16_t*)carve(DD * 2);
    w1t = (bf16_t*)carve(DF * 2);
    w2t = (bf16_t*)carve(DF * 2);
  }
  bf16_t* xb = (bf16_t*)carve(SD * 2);
  float* xf = (float*)carve(SD * 4);
  bf16_t* qkv = (bf16_t*)carve(3 * SD * 2);
  bf16_t* vt = (bf16_t*)carve(SD * 2);
  bf16_t* attnb = (bf16_t*)carve(SD * 2);
  bf16_t* hbuf = (bf16_t*)carve(SF * 2);
  float* tmp = (float*)carve(SD * 4);
  int* pids = (int*)carve(S_LEN * 4);
  // split-K partial buffer (4 f32 planes); only used if it fits
  float* ptmp = (float*)carve(4 * SD * 4);
  bool haveSplit = ((size_t)(p - (char*)d_ws) <= ws_size);

  posid_kernel<<<1, 256, 0, stream>>>(amask, pids);
  embed_kernel<<<S_LEN, 256, 0, stream>>>(ids, pids, emb_word, emb_pos,
                                          emb_type, emb_g, emb_b, xf, xb);

  if (full) {
    trc_kernel<<<dim3(12, 12, 12), 256, 0, stream>>>(Wq, qkvt, 768, 768, DD, 3 * DD);
    trc_kernel<<<dim3(12, 12, 12), 256, 0, stream>>>(Wk, qkvt + DD, 768, 768, DD, 3 * DD);
    trc_kernel<<<dim3(12, 12, 12), 256, 0, stream>>>(Wv, qkvt + 2 * DD, 768, 768, DD, 3 * DD);
    trc_kernel<<<dim3(12, 12, 12), 256, 0, stream>>>(Wo, wot, 768, 768, DD, DD);
    trc_kernel<<<dim3(48, 12, 12), 256, 0, stream>>>(W1, w1t, 768, 3072, DF, DF);
    trc_kernel<<<dim3(12, 48, 12), 256, 0, stream>>>(W2, w2t, 3072, 768, DF, DF);
  }

  for (int i = 0; i < NLAYER; ++i) {
    const bf16_t *qkvt_i, *wot_i, *w1t_i, *w2t_i;
    if (full) {
      qkvt_i = qkvt + (size_t)i * 3 * DD;
      wot_i = wot + (size_t)i * DD;
      w1t_i = w1t + (size_t)i * DF;
      w2t_i = w2t + (size_t)i * DF;
    } else {
      trc_kernel<<<dim3(12, 12, 1), 256, 0, stream>>>(Wq + (size_t)i * DD, qkvt, 768, 768, 0, 0);
      trc_kernel<<<dim3(12, 12, 1), 256, 0, stream>>>(Wk + (size_t)i * DD, qkvt + DD, 768, 768, 0, 0);
      trc_kernel<<<dim3(12, 12, 1), 256, 0, stream>>>(Wv + (size_t)i * DD, qkvt + 2 * DD, 768, 768, 0, 0);
      trc_kernel<<<dim3(12, 12, 1), 256, 0, stream>>>(Wo + (size_t)i * DD, wot, 768, 768, 0, 0);
      trc_kernel<<<dim3(48, 12, 1), 256, 0, stream>>>(W1 + (size_t)i * DF, w1t, 768, 3072, 0, 0);
      trc_kernel<<<dim3(12, 48, 1), 256, 0, stream>>>(W2 + (size_t)i * DF, w2t, 3072, 768, 0, 0);
      qkvt_i = qkvt; wot_i = wot; w1t_i = w1t; w2t_i = w2t;
    }
    gemm_kernel<0><<<dim3(6, 32, 3), 256, 0, stream>>>(
        xb, qkvt_i, (long)DD, bq + i * 768, bk + i * 768, bv + i * 768, qkv,
        (long)SD, nullptr, nullptr, S_LEN, 768, 768, 768);
    tr_kernel<<<dim3(12, 64, 1), 256, 0, stream>>>(qkv + 2 * SD, vt, 4096, 768);
    attn_kernel<<<dim3(64, 12), 64, 0, stream>>>(qkv, qkv + SD, vt, attnb);
    if (haveSplit) {
      gemm_kernel<3><<<dim3(6, 32, 2), 256, 0, stream>>>(
          attnb, wot_i, 0, nullptr, nullptr, nullptr, nullptr, 0, nullptr,
          ptmp, S_LEN, 768, 768, 384);
      lnred_kernel<<<S_LEN, 256, 0, stream>>>(ptmp, 2, bo + i * 768,
                                              ln1g + i * 768, ln1b + i * 768,
                                              xf, xb);
    } else {
      gemm_kernel<2><<<dim3(6, 32, 1), 256, 0, stream>>>(
          attnb, wot_i, 0, bo + i * 768, nullptr, nullptr, nullptr, 0, xf, tmp,
          S_LEN, 768, 768, 768);
      ln_kernel<<<S_LEN, 256, 0, stream>>>(tmp, ln1g + i * 768, ln1b + i * 768,
                                           xf, xb);
    }
    gemm_kernel<1><<<dim3(24, 32, 1), 256, 0, stream>>>(
        xb, w1t_i, 0, b1 + (size_t)i * FFDIM, nullptr, nullptr, hbuf, 0,
        nullptr, nullptr, S_LEN, FFDIM, 768, 768);
    if (haveSplit) {
      gemm_kernel<3><<<dim3(6, 32, 4), 256, 0, stream>>>(
          hbuf, w2t_i, 0, nullptr, nullptr, nullptr, nullptr, 0, nullptr,
          ptmp, S_LEN, 768, 3072, 768);
      lnred_kernel<<<S_LEN, 256, 0, stream>>>(ptmp, 4, b2 + i * 768,
                                              ln2g + i * 768, ln2b + i * 768,
                                              xf, xb);
    } else {
      gemm_kernel<2><<<dim3(6, 32, 1), 256, 0, stream>>>(
          hbuf, w2t_i, 0, b2 + i * 768, nullptr, nullptr, nullptr, 0, xf, tmp,
          S_LEN, 768, 3072, 3072);
      ln_kernel<<<S_LEN, 256, 0, stream>>>(tmp, ln2g + i * 768, ln2b + i * 768,
                                           xf, xb);
    }
  }
  cls_kernel<<<2, 256, 0, stream>>>(xf, cW1, cb1, cW2, cb2, dW1, db1, dW2, db2, outp);
}

// Round 4
// 3595.965 us; speedup vs baseline: 1.1824x; 1.0422x over previous
//
#include <hip/hip_runtime.h>
#include <hip/hip_bf16.h>
#include <math.h>

typedef __bf16 bf16_t;
typedef __bf16 bf16x8 __attribute__((ext_vector_type(8)));
typedef __bf16 bf16x4 __attribute__((ext_vector_type(4)));
typedef float  f32x4  __attribute__((ext_vector_type(4)));
typedef short  s16x4  __attribute__((ext_vector_type(4)));

#define S_LEN 4096
#define DMODEL 768
#define NHEAD 12
#define NLAYER 12
#define FFDIM 3072

// ---- MFMA helpers -------------------------------------------------------
static __device__ inline f32x4 mfma16x16x16(bf16x4 a, bf16x4 b, f32x4 c) {
#if __has_builtin(__builtin_amdgcn_mfma_f32_16x16x16_bf16)
  return __builtin_amdgcn_mfma_f32_16x16x16_bf16(a, b, c, 0, 0, 0);
#else
  return __builtin_amdgcn_mfma_f32_16x16x16bf16_1k(
      __builtin_bit_cast(s16x4, a), __builtin_bit_cast(s16x4, b), c, 0, 0, 0);
#endif
}

// async global -> LDS, 16B per lane. LDS dest is wave-uniform base + lane*16.
static __device__ inline void gload_lds16(const void* g, void* l) {
  __builtin_amdgcn_global_load_lds(
      (const __attribute__((address_space(1))) void*)g,
      (__attribute__((address_space(3))) void*)l, 16, 0, 0);
}

// ---- pos_ids = cumsum(mask)*mask + 1 (B=1, S=4096) ----------------------
__global__ __launch_bounds__(256) void posid_kernel(const int* __restrict__ m,
                                                    int* __restrict__ pids) {
  __shared__ int ps[256];
  int t = threadIdx.x;
  int base = t * 16;
  int loc[16], mv[16];
  int s = 0;
#pragma unroll
  for (int j = 0; j < 16; ++j) { mv[j] = m[base + j]; s += mv[j]; loc[j] = s; }
  ps[t] = s;
  __syncthreads();
  for (int off = 1; off < 256; off <<= 1) {
    int v = (t >= off) ? ps[t - off] : 0;
    __syncthreads();
    ps[t] += v;
    __syncthreads();
  }
  int pre = t ? ps[t - 1] : 0;
#pragma unroll
  for (int j = 0; j < 16; ++j) pids[base + j] = (pre + loc[j]) * mv[j] + 1;
}

// ---- block reduction helper (256 threads) -------------------------------
__device__ inline float blk_sum(float v, float* sred) {
#pragma unroll
  for (int o = 32; o; o >>= 1) v += __shfl_down(v, o, 64);
  int w = threadIdx.x >> 6;
  __syncthreads();
  if ((threadIdx.x & 63) == 0) sred[w] = v;
  __syncthreads();
  return sred[0] + sred[1] + sred[2] + sred[3];
}

// ---- embedding gather + LN (f32 inputs) ----------------------------------
__global__ __launch_bounds__(256) void embed_kernel(
    const int* __restrict__ ids, const int* __restrict__ pids,
    const float* __restrict__ ew, const float* __restrict__ ep,
    const float* __restrict__ et, const float* __restrict__ g,
    const float* __restrict__ b, float* __restrict__ xf,
    bf16_t* __restrict__ xb) {
  __shared__ float sred[4];
  int s = blockIdx.x, t = threadIdx.x;
  long wb = (long)ids[s] * DMODEL;
  long pb = (long)pids[s] * DMODEL;
  float v[3];
#pragma unroll
  for (int j = 0; j < 3; ++j) {
    int d = t + j * 256;
    v[j] = ew[wb + d] + ep[pb + d] + et[d];
  }
  float mu = blk_sum(v[0] + v[1] + v[2], sred) * (1.0f / 768.0f);
  float ss = 0.f;
#pragma unroll
  for (int j = 0; j < 3; ++j) { v[j] -= mu; ss += v[j] * v[j]; }
  float rs = rsqrtf(blk_sum(ss, sred) * (1.0f / 768.0f) + 1e-5f);
#pragma unroll
  for (int j = 0; j < 3; ++j) {
    int d = t + j * 256;
    float o = v[j] * rs * g[d] + b[d];
    xf[(long)s * DMODEL + d] = o;
    xb[(long)s * DMODEL + d] = (bf16_t)o;
  }
}

// ---- LN over f32 tmp -> xf (f32 master) + xb (bf16 mirror) ---------------
__global__ __launch_bounds__(256) void ln_kernel(
    const float* __restrict__ in, const float* __restrict__ g,
    const float* __restrict__ b, float* __restrict__ xf,
    bf16_t* __restrict__ xb) {
  __shared__ float sred[4];
  int row = blockIdx.x, t = threadIdx.x;
  const float* r = in + (long)row * DMODEL;
  float v[3] = {r[t], r[t + 256], r[t + 512]};
  float mu = blk_sum(v[0] + v[1] + v[2], sred) * (1.0f / 768.0f);
  float ss = 0.f;
#pragma unroll
  for (int j = 0; j < 3; ++j) { v[j] -= mu; ss += v[j] * v[j]; }
  float rs = rsqrtf(blk_sum(ss, sred) * (1.0f / 768.0f) + 1e-5f);
#pragma unroll
  for (int j = 0; j < 3; ++j) {
    int d = t + j * 256;
    float o = v[j] * rs * g[d] + b[d];
    xf[(long)row * DMODEL + d] = o;
    xb[(long)row * DMODEL + d] = (bf16_t)o;
  }
}

// ---- LN over (sum of ns split-K partials + gemm bias + residual xf) ------
// val[d] = sum_z pt[z][row][d] + gb[d] + xf[row][d]; then LN -> xf, xb.
__global__ __launch_bounds__(256) void lnred_kernel(
    const float* __restrict__ pt, int ns, const float* __restrict__ gb,
    const float* __restrict__ g, const float* __restrict__ b,
    float* __restrict__ xf, bf16_t* __restrict__ xb) {
  __shared__ float sred[4];
  const long MN = (long)S_LEN * DMODEL;
  int row = blockIdx.x, t = threadIdx.x;
  long rb = (long)row * DMODEL;
  float v[3];
#pragma unroll
  for (int j = 0; j < 3; ++j) {
    int d = t + j * 256;
    float a = gb[d] + xf[rb + d];
    for (int z = 0; z < ns; ++z) a += pt[(long)z * MN + rb + d];
    v[j] = a;
  }
  float mu = blk_sum(v[0] + v[1] + v[2], sred) * (1.0f / 768.0f);
  float ss = 0.f;
#pragma unroll
  for (int j = 0; j < 3; ++j) { v[j] -= mu; ss += v[j] * v[j]; }
  float rs = rsqrtf(blk_sum(ss, sred) * (1.0f / 768.0f) + 1e-5f);
#pragma unroll
  for (int j = 0; j < 3; ++j) {
    int d = t + j * 256;
    float o = v[j] * rs * g[d] + b[d];
    xf[rb + d] = o;
    xb[rb + d] = (bf16_t)o;
  }
}

// ---- f32 -> bf16 transpose (weights), 64x64 tiles ------------------------
__global__ __launch_bounds__(256) void trc_kernel(const float* __restrict__ src,
                                                  bf16_t* __restrict__ dst,
                                                  int R, int C, long srcStride,
                                                  long dstStride) {
  src += (long)blockIdx.z * srcStride;
  dst += (long)blockIdx.z * dstStride;
  __shared__ float tile[64][65];
  int r0 = blockIdx.y * 64, c0 = blockIdx.x * 64;
  int t = threadIdx.x;
  int tr = t >> 4;
  int tc = (t & 15) * 4;
#pragma unroll
  for (int j = 0; j < 4; ++j) {
    int row = tr + j * 16;
    float4 v = *(const float4*)(src + (long)(r0 + row) * C + c0 + tc);
    tile[row][tc] = v.x; tile[row][tc + 1] = v.y;
    tile[row][tc + 2] = v.z; tile[row][tc + 3] = v.w;
  }
  __syncthreads();
#pragma unroll
  for (int j = 0; j < 4; ++j) {
    int row = tr + j * 16;  // dst row within tile (= src col)
    bf16x4 v;
    v[0] = (bf16_t)tile[tc + 0][row]; v[1] = (bf16_t)tile[tc + 1][row];
    v[2] = (bf16_t)tile[tc + 2][row]; v[3] = (bf16_t)tile[tc + 3][row];
    *(bf16x4*)(dst + (long)(c0 + row) * R + r0 + tc) = v;
  }
}

// ---- bf16 -> bf16 transpose (V), 64x64 tiles ------------------------------
__global__ __launch_bounds__(256) void tr_kernel(const bf16_t* __restrict__ src,
                                                 bf16_t* __restrict__ dst,
                                                 int R, int C) {
  __shared__ bf16_t tile[64][68];
  int r0 = blockIdx.y * 64, c0 = blockIdx.x * 64;
  int t = threadIdx.x;
  int tr = t >> 4;
  int tc = (t & 15) * 4;
#pragma unroll
  for (int j = 0; j < 4; ++j) {
    int row = tr + j * 16;
    bf16x4 v = *(const bf16x4*)(src + (long)(r0 + row) * C + c0 + tc);
    tile[row][tc] = v[0]; tile[row][tc + 1] = v[1];
    tile[row][tc + 2] = v[2]; tile[row][tc + 3] = v[3];
  }
  __syncthreads();
#pragma unroll
  for (int j = 0; j < 4; ++j) {
    int row = tr + j * 16;
    bf16x4 v;
    v[0] = tile[tc + 0][row]; v[1] = tile[tc + 1][row];
    v[2] = tile[tc + 2][row]; v[3] = tile[tc + 3][row];
    *(bf16x4*)(dst + (long)(c0 + row) * R + r0 + tc) = v;
  }
}

// ---- main GEMM: C = A(MxK) * Bt(NxK)^T + bias, 128x128 tile, BK=64 -------
// m97 structure: single 32 KB LDS buffer, global_load_lds width-16 staging,
// 2 barriers per K-step. Relies on >=2 co-resident blocks/CU for overlap
// (32 KB LDS -> up to 5 blocks/CU). Split-K (EP 3) raises small grids to
// 3 blocks/CU. XCD-aware bijective block swizzle (all grids have nwg%8==0).
// EP 0: out = bf16(acc + bias); z = weight set      (QKV)
// EP 1: out = bf16(gelu(acc + bias))                (FF1)
// EP 2: tmp = acc + bias + resf (f32)               (fallback proj/FF2)
// EP 3: tmp[z] = acc (f32 partial); z = K-chunk     (split-K proj/FF2)
template <int EP>
__global__ __launch_bounds__(256) void gemm_kernel(
    const bf16_t* __restrict__ A, const bf16_t* __restrict__ Bt, long btStride,
    const float* b0, const float* b1, const float* b2,
    bf16_t* __restrict__ out, long outStride, const float* __restrict__ resf,
    float* __restrict__ tmp, int M, int N, int K, int kc) {
  int z = blockIdx.z;
  const float* bias = nullptr;
  int kBeg = 0;
  if constexpr (EP == 3) {
    kBeg = z * kc;  // K-chunk
  } else {
    Bt += (long)z * btStride;
    bias = (z == 0) ? b0 : (z == 1 ? b1 : b2);
    out += (long)z * outStride;
  }

  // XCD-aware bijective swizzle (requires nwg % 8 == 0; holds: 192/768)
  int nwg = gridDim.x * gridDim.y;
  int bid = blockIdx.y * gridDim.x + blockIdx.x;
  int swz = (bid & 7) * (nwg >> 3) + (bid >> 3);
  int bx = swz % gridDim.x;
  int by = swz / gridDim.x;

  int tid = threadIdx.x;
  int lane = tid & 63;
  int wave = tid >> 6;
  int wm = (wave >> 1) * 64;
  int wn = (wave & 1) * 64;
  int l15 = lane & 15;
  int g4 = lane >> 4;
  int m0 = by * 128;
  int n0 = bx * 128;

  f32x4 acc[4][4] = {};

  // layout: [k-octet g(0..7)][row(0..127)] x 8 contiguous bf16
  __shared__ __align__(16) bf16_t As[128 * 64];
  __shared__ __align__(16) bf16_t Bs[128 * 64];

  for (int kt = kBeg; kt < kBeg + kc; kt += 64) {
    // stage: 8 x 1KB global_load_lds per wave (A and B tiles)
#pragma unroll
    for (int c = 0; c < 4; ++c) {
      int L0 = c * 256 + wave * 64;   // wave-uniform LDS base (16B units)
      int row = (L0 & 127) + lane;    // lane's source row
      int gg = L0 >> 7;               // k-octet for this issue
      gload_lds16(A + (long)(m0 + row) * K + kt + gg * 8, As + L0 * 8);
      gload_lds16(Bt + (long)(n0 + row) * K + kt + gg * 8, Bs + L0 * 8);
    }
    __syncthreads();  // drains vmcnt(0): staged data visible to all waves
#pragma unroll
    for (int ks = 0; ks < 2; ++ks) {
      bf16x8 af[4], bfr[4];
#pragma unroll
      for (int mt = 0; mt < 4; ++mt)
        af[mt] = *(const bf16x8*)(As + (((ks * 4 + g4) * 128) + wm + mt * 16 + l15) * 8);
#pragma unroll
      for (int nt = 0; nt < 4; ++nt)
        bfr[nt] = *(const bf16x8*)(Bs + (((ks * 4 + g4) * 128) + wn + nt * 16 + l15) * 8);
#pragma unroll
      for (int mt = 0; mt < 4; ++mt)
#pragma unroll
        for (int nt = 0; nt < 4; ++nt)
          acc[mt][nt] = __builtin_amdgcn_mfma_f32_16x16x32_bf16(
              af[mt], bfr[nt], acc[mt][nt], 0, 0, 0);
    }
    __syncthreads();  // all waves done reading As/Bs before next stage
  }

#pragma unroll
  for (int mt = 0; mt < 4; ++mt)
#pragma unroll
    for (int nt = 0; nt < 4; ++nt) {
      int col = n0 + wn + nt * 16 + l15;
      float bval = (EP == 3) ? 0.f : bias[col];
#pragma unroll
      for (int r = 0; r < 4; ++r) {
        int row = m0 + wm + mt * 16 + g4 * 4 + r;
        float v = acc[mt][nt][r] + bval;
        if (EP == 0) {
          out[(long)row * N + col] = (bf16_t)v;
        } else if (EP == 1) {
          float ge = 0.5f * v * (1.0f + erff(v * 0.70710678118654752f));
          out[(long)row * N + col] = (bf16_t)ge;
        } else if (EP == 2) {
          tmp[(long)row * N + col] = v + resf[(long)row * N + col];
        } else {
          tmp[(long)z * ((long)M * N) + (long)row * N + col] = v;
        }
      }
    }
}

// ---- sliding-window flash attention --------------------------------------
// grid (S/32, H), block 64 (1 wave), 32 q-rows per wave -> 1536 waves =
// 6 waves/CU (was 3 at 64 q-rows) for latency hiding.
// q,k: (S,768) bf16; vt: (768,S) bf16.
#define NEGM 30000.0f
__global__ __launch_bounds__(64) void attn_kernel(
    const bf16_t* __restrict__ q, const bf16_t* __restrict__ k,
    const bf16_t* __restrict__ vt, bf16_t* __restrict__ outb) {
  int qt = blockIdx.x * 32;
  int hcol = blockIdx.y * 64;
  int lane = threadIdx.x;
  int l15 = lane & 15, g4 = lane >> 4;
  __shared__ __align__(16) float sbuf[32];

  // Q fragments (B-operand of St = K @ Q^T), scale 1/8 folded in (exact).
  bf16x8 qf[2][2];
#pragma unroll
  for (int nt = 0; nt < 2; ++nt)
#pragma unroll
    for (int ks = 0; ks < 2; ++ks) {
      bf16x8 t = *(const bf16x8*)(q + (long)(qt + nt * 16 + l15) * DMODEL +
                                  hcol + ks * 32 + g4 * 8);
#pragma unroll
      for (int i = 0; i < 8; ++i) t[i] = (bf16_t)((float)t[i] * 0.125f);
      qf[nt][ks] = t;
    }

  f32x4 o[2][4] = {};   // [qmt][dt]; lane r -> O[q=16qmt+4g4+r][d=16dt+l15]
  float mS[2], lS[2];
#pragma unroll
  for (int nt = 0; nt < 2; ++nt) { mS[nt] = -NEGM; lS[nt] = 0.f; }

  // 64-aligned key window covering [qt-256, qt+31+256]; overshoot is masked.
  int kstart = (qt >= 256) ? ((qt - 256) & ~63) : 0;
  int kend = (qt + 288 + 63) & ~63;
  if (kend > S_LEN) kend = S_LEN;

  for (int kb = kstart; kb < kend; kb += 64) {
    // St = K_chunk @ Q^T -> St[key=16kt+4g4+r][q=16nt+l15]
    bf16x8 kf[4][2];
#pragma unroll
    for (int kt = 0; kt < 4; ++kt)
#pragma unroll
      for (int ks = 0; ks < 2; ++ks)
        kf[kt][ks] = *(const bf16x8*)(k + (long)(kb + kt * 16 + l15) * DMODEL +
                                      hcol + ks * 32 + g4 * 8);
    f32x4 st[4][2] = {};
#pragma unroll
    for (int kt = 0; kt < 4; ++kt)
#pragma unroll
      for (int nt = 0; nt < 2; ++nt) {
        st[kt][nt] = __builtin_amdgcn_mfma_f32_16x16x32_bf16(
            kf[kt][0], qf[nt][0], st[kt][nt], 0, 0, 0);
        st[kt][nt] = __builtin_amdgcn_mfma_f32_16x16x32_bf16(
            kf[kt][1], qf[nt][1], st[kt][nt], 0, 0, 0);
      }
    // band mask + online softmax stats (per query q = 16nt + l15)
    float alpha[2];
#pragma unroll
    for (int nt = 0; nt < 2; ++nt) {
      int qg = qt + nt * 16 + l15;
      float mx = -NEGM;
#pragma unroll
      for (int kt = 0; kt < 4; ++kt)
#pragma unroll
        for (int r = 0; r < 4; ++r) {
          int kg = kb + kt * 16 + g4 * 4 + r;
          bool valid = (kg >= qg - 256) && (kg <= qg + 256);
          float s = valid ? st[kt][nt][r] : -NEGM;
          st[kt][nt][r] = s;
          mx = fmaxf(mx, s);
        }
      mx = fmaxf(mx, __shfl_xor(mx, 16, 64));
      mx = fmaxf(mx, __shfl_xor(mx, 32, 64));
      float mnew = fmaxf(mS[nt], mx);
      alpha[nt] = exp2f((mS[nt] - mnew) * 1.44269504088896f);
      float ls = 0.f;
#pragma unroll
      for (int kt = 0; kt < 4; ++kt)
#pragma unroll
        for (int r = 0; r < 4; ++r) {
          float p = exp2f((st[kt][nt][r] - mnew) * 1.44269504088896f);
          st[kt][nt][r] = p;
          ls += p;
        }
      ls += __shfl_xor(ls, 16, 64);
      ls += __shfl_xor(ls, 32, 64);
      lS[nt] = lS[nt] * alpha[nt] + ls;
      mS[nt] = mnew;
    }
    // broadcast alpha into O-layout
    if (g4 == 0) {
#pragma unroll
      for (int nt = 0; nt < 2; ++nt) sbuf[nt * 16 + l15] = alpha[nt];
    }
    __syncthreads();
    f32x4 av[2];
#pragma unroll
    for (int qmt = 0; qmt < 2; ++qmt)
      av[qmt] = *(const f32x4*)(sbuf + qmt * 16 + g4 * 4);
#pragma unroll
    for (int qmt = 0; qmt < 2; ++qmt)
#pragma unroll
      for (int dt = 0; dt < 4; ++dt)
#pragma unroll
        for (int r = 0; r < 4; ++r) o[qmt][dt][r] *= av[qmt][r];
    // PV: St lanes are already exactly the A-operand of 16x16x16 MFMA.
#pragma unroll
    for (int kt = 0; kt < 4; ++kt) {
      bf16x4 pa[2];
#pragma unroll
      for (int qmt = 0; qmt < 2; ++qmt)
#pragma unroll
        for (int i = 0; i < 4; ++i) pa[qmt][i] = (bf16_t)st[kt][qmt][i];
      bf16x4 vf[4];
#pragma unroll
      for (int dt = 0; dt < 4; ++dt)
        vf[dt] = *(const bf16x4*)(vt + (long)(hcol + dt * 16 + l15) * S_LEN +
                                  kb + kt * 16 + g4 * 4);
#pragma unroll
      for (int qmt = 0; qmt < 2; ++qmt)
#pragma unroll
        for (int dt = 0; dt < 4; ++dt)
          o[qmt][dt] = mfma16x16x16(pa[qmt], vf[dt], o[qmt][dt]);
    }
    __syncthreads();
  }
  // final normalize by l
  if (g4 == 0) {
#pragma unroll
    for (int nt = 0; nt < 2; ++nt) sbuf[nt * 16 + l15] = lS[nt];
  }
  __syncthreads();
  f32x4 lv[2];
#pragma unroll
  for (int qmt = 0; qmt < 2; ++qmt)
    lv[qmt] = *(const f32x4*)(sbuf + qmt * 16 + g4 * 4);
#pragma unroll
  for (int qmt = 0; qmt < 2; ++qmt)
#pragma unroll
    for (int dt = 0; dt < 4; ++dt)
#pragma unroll
      for (int r = 0; r < 4; ++r)
        outb[(long)(qt + qmt * 16 + g4 * 4 + r) * DMODEL + hcol + dt * 16 +
             l15] = (bf16_t)(o[qmt][dt][r] / lv[qmt][r]);
}

// ---- classifier stage 1: h = relu(pooled @ W1 + b1), parallel ------------
// grid (8, 2): x = 64-col group, y = head (0=century, 1=decade).
// 256 threads: col = t&63 (+group*64), k-chunk (t>>6)*192; LDS reduce by 4.
__global__ __launch_bounds__(256) void cls1_kernel(
    const float* __restrict__ xf, const float* cW1, const float* cb1,
    const float* dW1, const float* db1, float* __restrict__ hws) {
  __shared__ float red[4][64];
  bool dec = (blockIdx.y == 1);
  const float* W1 = dec ? dW1 : cW1;
  const float* B1 = dec ? db1 : cb1;
  float* h = hws + (dec ? 512 : 0);
  int t = threadIdx.x;
  int c = (t & 63) + blockIdx.x * 64;
  int ch = t >> 6;
  float s = 0.f;
  for (int k2 = ch * 192; k2 < ch * 192 + 192; ++k2)
    s += xf[k2] * W1[(long)k2 * 512 + c];
  red[ch][t & 63] = s;
  __syncthreads();
  if (t < 64) {
    int col = t + blockIdx.x * 64;
    float a = red[0][t] + red[1][t] + red[2][t] + red[3][t] + B1[col];
    h[col] = fmaxf(a, 0.f);
  }
}

// ---- classifier stage 2: out = h @ W2 + b2 (tiny) -------------------------
__global__ __launch_bounds__(256) void cls2_kernel(
    const float* __restrict__ hws, const float* cW2, const float* cb2,
    const float* dW2, const float* db2, float* __restrict__ out) {
  __shared__ float sred[4];
  bool dec = (blockIdx.x == 1);
  const float* W2 = dec ? dW2 : cW2;
  const float* B2 = dec ? db2 : cb2;
  const float* h = hws + (dec ? 512 : 0);
  int nout = dec ? 10 : 5;
  float* op = out + (dec ? 5 : 0);
  int t = threadIdx.x;
  float h0 = h[t], h1 = h[t + 256];
  for (int o = 0; o < nout; ++o) {
    float s = h0 * W2[t * nout + o] + h1 * W2[(t + 256) * nout + o];
    float tot = blk_sum(s, sred);
    if (t == 0) op[o] = tot + B2[o];
    __syncthreads();
  }
}

// ---- host orchestration --------------------------------------------------
extern "C" void kernel_launch(void* const* d_in, const int* in_sizes, int n_in,
                              void* d_out, int out_size, void* d_ws,
                              size_t ws_size, hipStream_t stream) {
  const int* ids = (const int*)d_in[0];
  const int* amask = (const int*)d_in[1];
  const float* emb_word = (const float*)d_in[2];
  const float* emb_pos = (const float*)d_in[3];
  const float* emb_type = (const float*)d_in[4];
  const float* emb_g = (const float*)d_in[5];
  const float* emb_b = (const float*)d_in[6];
  const float* Wq = (const float*)d_in[7];
  const float* bq = (const float*)d_in[8];
  const float* Wk = (const float*)d_in[9];
  const float* bk = (const float*)d_in[10];
  const float* Wv = (const float*)d_in[11];
  const float* bv = (const float*)d_in[12];
  const float* Wo = (const float*)d_in[13];
  const float* bo = (const float*)d_in[14];
  const float* ln1g = (const float*)d_in[15];
  const float* ln1b = (const float*)d_in[16];
  const float* W1 = (const float*)d_in[17];
  const float* b1 = (const float*)d_in[18];
  const float* W2 = (const float*)d_in[19];
  const float* b2 = (const float*)d_in[20];
  const float* ln2g = (const float*)d_in[21];
  const float* ln2b = (const float*)d_in[22];
  const float* cW1 = (const float*)d_in[23];
  const float* cb1 = (const float*)d_in[24];
  const float* cW2 = (const float*)d_in[25];
  const float* cb2 = (const float*)d_in[26];
  const float* dW1 = (const float*)d_in[27];
  const float* db1 = (const float*)d_in[28];
  const float* dW2 = (const float*)d_in[29];
  const float* db2 = (const float*)d_in[30];
  float* outp = (float*)d_out;

  const size_t SD = (size_t)S_LEN * DMODEL;
  const size_t DD = (size_t)DMODEL * DMODEL;
  const size_t DF = (size_t)DMODEL * FFDIM;
  const size_t SF = (size_t)S_LEN * FFDIM;

  char* p = (char*)d_ws;
  auto carve = [&](size_t bytes) {
    char* r = p;
    p += (bytes + 255) & ~(size_t)255;
    return (void*)r;
  };

  size_t actsBytes = SD * 2 + SD * 4 + 3 * SD * 2 + SD * 2 + SD * 2 + SF * 2 +
                     SD * 4 + S_LEN * 4 + 16 * 256;
  size_t fullW = (36 * DD + 12 * DD + 24 * DF) * 2 + 16 * 256;
  bool full = ws_size >= actsBytes + fullW;

  bf16_t *qkvt, *wot, *w1t, *w2t;
  if (full) {
    qkvt = (bf16_t*)carve(36 * DD * 2);
    wot = (bf16_t*)carve(12 * DD * 2);
    w1t = (bf16_t*)carve(12 * DF * 2);
    w2t = (bf16_t*)carve(12 * DF * 2);
  } else {
    qkvt = (bf16_t*)carve(3 * DD * 2);
    wot = (bf16_t*)carve(DD * 2);
    w1t = (bf16_t*)carve(DF * 2);
    w2t = (bf16_t*)carve(DF * 2);
  }
  bf16_t* xb = (bf16_t*)carve(SD * 2);
  float* xf = (float*)carve(SD * 4);
  bf16_t* qkv = (bf16_t*)carve(3 * SD * 2);
  bf16_t* vt = (bf16_t*)carve(SD * 2);
  bf16_t* attnb = (bf16_t*)carve(SD * 2);
  bf16_t* hbuf = (bf16_t*)carve(SF * 2);
  float* tmp = (float*)carve(SD * 4);
  int* pids = (int*)carve(S_LEN * 4);
  float* hws = (float*)carve(1024 * 4);  // classifier hidden (2 heads x 512)
  // split-K partial buffer (4 f32 planes); only used if it fits
  float* ptmp = (float*)carve(4 * SD * 4);
  bool haveSplit = ((size_t)(p - (char*)d_ws) <= ws_size);

  posid_kernel<<<1, 256, 0, stream>>>(amask, pids);
  embed_kernel<<<S_LEN, 256, 0, stream>>>(ids, pids, emb_word, emb_pos,
                                          emb_type, emb_g, emb_b, xf, xb);

  if (full) {
    trc_kernel<<<dim3(12, 12, 12), 256, 0, stream>>>(Wq, qkvt, 768, 768, DD, 3 * DD);
    trc_kernel<<<dim3(12, 12, 12), 256, 0, stream>>>(Wk, qkvt + DD, 768, 768, DD, 3 * DD);
    trc_kernel<<<dim3(12, 12, 12), 256, 0, stream>>>(Wv, qkvt + 2 * DD, 768, 768, DD, 3 * DD);
    trc_kernel<<<dim3(12, 12, 12), 256, 0, stream>>>(Wo, wot, 768, 768, DD, DD);
    trc_kernel<<<dim3(48, 12, 12), 256, 0, stream>>>(W1, w1t, 768, 3072, DF, DF);
    trc_kernel<<<dim3(12, 48, 12), 256, 0, stream>>>(W2, w2t, 3072, 768, DF, DF);
  }

  for (int i = 0; i < NLAYER; ++i) {
    const bf16_t *qkvt_i, *wot_i, *w1t_i, *w2t_i;
    if (full) {
      qkvt_i = qkvt + (size_t)i * 3 * DD;
      wot_i = wot + (size_t)i * DD;
      w1t_i = w1t + (size_t)i * DF;
      w2t_i = w2t + (size_t)i * DF;
    } else {
      trc_kernel<<<dim3(12, 12, 1), 256, 0, stream>>>(Wq + (size_t)i * DD, qkvt, 768, 768, 0, 0);
      trc_kernel<<<dim3(12, 12, 1), 256, 0, stream>>>(Wk + (size_t)i * DD, qkvt + DD, 768, 768, 0, 0);
      trc_kernel<<<dim3(12, 12, 1), 256, 0, stream>>>(Wv + (size_t)i * DD, qkvt + 2 * DD, 768, 768, 0, 0);
      trc_kernel<<<dim3(12, 12, 1), 256, 0, stream>>>(Wo + (size_t)i * DD, wot, 768, 768, 0, 0);
      trc_kernel<<<dim3(48, 12, 1), 256, 0, stream>>>(W1 + (size_t)i * DF, w1t, 768, 3072, 0, 0);
      trc_kernel<<<dim3(12, 48, 1), 256, 0, stream>>>(W2 + (size_t)i * DF, w2t, 3072, 768, 0, 0);
      qkvt_i = qkvt; wot_i = wot; w1t_i = w1t; w2t_i = w2t;
    }
    gemm_kernel<0><<<dim3(6, 32, 3), 256, 0, stream>>>(
        xb, qkvt_i, (long)DD, bq + i * 768, bk + i * 768, bv + i * 768, qkv,
        (long)SD, nullptr, nullptr, S_LEN, 768, 768, 768);
    tr_kernel<<<dim3(12, 64, 1), 256, 0, stream>>>(qkv + 2 * SD, vt, 4096, 768);
    attn_kernel<<<dim3(128, 12), 64, 0, stream>>>(qkv, qkv + SD, vt, attnb);
    if (haveSplit) {
      gemm_kernel<3><<<dim3(6, 32, 2), 256, 0, stream>>>(
          attnb, wot_i, 0, nullptr, nullptr, nullptr, nullptr, 0, nullptr,
          ptmp, S_LEN, 768, 768, 384);
      lnred_kernel<<<S_LEN, 256, 0, stream>>>(ptmp, 2, bo + i * 768,
                                              ln1g + i * 768, ln1b + i * 768,
                                              xf, xb);
    } else {
      gemm_kernel<2><<<dim3(6, 32, 1), 256, 0, stream>>>(
          attnb, wot_i, 0, bo + i * 768, nullptr, nullptr, nullptr, 0, xf, tmp,
          S_LEN, 768, 768, 768);
      ln_kernel<<<S_LEN, 256, 0, stream>>>(tmp, ln1g + i * 768, ln1b + i * 768,
                                           xf, xb);
    }
    gemm_kernel<1><<<dim3(24, 32, 1), 256, 0, stream>>>(
        xb, w1t_i, 0, b1 + (size_t)i * FFDIM, nullptr, nullptr, hbuf, 0,
        nullptr, nullptr, S_LEN, FFDIM, 768, 768);
    if (haveSplit) {
      gemm_kernel<3><<<dim3(6, 32, 4), 256, 0, stream>>>(
          hbuf, w2t_i, 0, nullptr, nullptr, nullptr, nullptr, 0, nullptr,
          ptmp, S_LEN, 768, 3072, 768);
      lnred_kernel<<<S_LEN, 256, 0, stream>>>(ptmp, 4, b2 + i * 768,
                                              ln2g + i * 768, ln2b + i * 768,
                                              xf, xb);
    } else {
      gemm_kernel<2><<<dim3(6, 32, 1), 256, 0, stream>>>(
          hbuf, w2t_i, 0, b2 + i * 768, nullptr, nullptr, nullptr, 0, xf, tmp,
          S_LEN, 768, 3072, 3072);
      ln_kernel<<<S_LEN, 256, 0, stream>>>(tmp, ln2g + i * 768, ln2b + i * 768,
                                           xf, xb);
    }
  }
  cls1_kernel<<<dim3(8, 2), 256, 0, stream>>>(xf, cW1, cb1, dW1, db1, hws);
  cls2_kernel<<<2, 256, 0, stream>>>(hws, cW2, cb2, dW2, db2, outp);
}

// Round 5
// 3579.662 us; speedup vs baseline: 1.1878x; 1.0046x over previous
//
#include <hip/hip_runtime.h>
#include <hip/hip_bf16.h>
#include <math.h>

typedef __bf16 bf16_t;
typedef __bf16 bf16x8 __attribute__((ext_vector_type(8)));
typedef __bf16 bf16x4 __attribute__((ext_vector_type(4)));
typedef float  f32x4  __attribute__((ext_vector_type(4)));
typedef short  s16x4  __attribute__((ext_vector_type(4)));

#define S_LEN 4096
#define DMODEL 768
#define NHEAD 12
#define NLAYER 12
#define FFDIM 3072

// ---- MFMA helpers -------------------------------------------------------
static __device__ inline f32x4 mfma16x16x16(bf16x4 a, bf16x4 b, f32x4 c) {
#if __has_builtin(__builtin_amdgcn_mfma_f32_16x16x16_bf16)
  return __builtin_amdgcn_mfma_f32_16x16x16_bf16(a, b, c, 0, 0, 0);
#else
  return __builtin_amdgcn_mfma_f32_16x16x16bf16_1k(
      __builtin_bit_cast(s16x4, a), __builtin_bit_cast(s16x4, b), c, 0, 0, 0);
#endif
}

// async global -> LDS, 16B per lane. LDS dest is wave-uniform base + lane*16.
static __device__ inline void gload_lds16(const void* g, void* l) {
  __builtin_amdgcn_global_load_lds(
      (const __attribute__((address_space(1))) void*)g,
      (__attribute__((address_space(3))) void*)l, 16, 0, 0);
}

// ---- pos_ids = cumsum(mask)*mask + 1 (B=1, S=4096) ----------------------
__global__ __launch_bounds__(256) void posid_kernel(const int* __restrict__ m,
                                                    int* __restrict__ pids) {
  __shared__ int ps[256];
  int t = threadIdx.x;
  int base = t * 16;
  int loc[16], mv[16];
  int s = 0;
#pragma unroll
  for (int j = 0; j < 16; ++j) { mv[j] = m[base + j]; s += mv[j]; loc[j] = s; }
  ps[t] = s;
  __syncthreads();
  for (int off = 1; off < 256; off <<= 1) {
    int v = (t >= off) ? ps[t - off] : 0;
    __syncthreads();
    ps[t] += v;
    __syncthreads();
  }
  int pre = t ? ps[t - 1] : 0;
#pragma unroll
  for (int j = 0; j < 16; ++j) pids[base + j] = (pre + loc[j]) * mv[j] + 1;
}

// ---- block reduction helper (256 threads) -------------------------------
__device__ inline float blk_sum(float v, float* sred) {
#pragma unroll
  for (int o = 32; o; o >>= 1) v += __shfl_down(v, o, 64);
  int w = threadIdx.x >> 6;
  __syncthreads();
  if ((threadIdx.x & 63) == 0) sred[w] = v;
  __syncthreads();
  return sred[0] + sred[1] + sred[2] + sred[3];
}

// ---- embedding gather + LN (f32 inputs) ----------------------------------
__global__ __launch_bounds__(256) void embed_kernel(
    const int* __restrict__ ids, const int* __restrict__ pids,
    const float* __restrict__ ew, const float* __restrict__ ep,
    const float* __restrict__ et, const float* __restrict__ g,
    const float* __restrict__ b, float* __restrict__ xf,
    bf16_t* __restrict__ xb) {
  __shared__ float sred[4];
  int s = blockIdx.x, t = threadIdx.x;
  long wb = (long)ids[s] * DMODEL;
  long pb = (long)pids[s] * DMODEL;
  float v[3];
#pragma unroll
  for (int j = 0; j < 3; ++j) {
    int d = t + j * 256;
    v[j] = ew[wb + d] + ep[pb + d] + et[d];
  }
  float mu = blk_sum(v[0] + v[1] + v[2], sred) * (1.0f / 768.0f);
  float ss = 0.f;
#pragma unroll
  for (int j = 0; j < 3; ++j) { v[j] -= mu; ss += v[j] * v[j]; }
  float rs = rsqrtf(blk_sum(ss, sred) * (1.0f / 768.0f) + 1e-5f);
#pragma unroll
  for (int j = 0; j < 3; ++j) {
    int d = t + j * 256;
    float o = v[j] * rs * g[d] + b[d];
    xf[(long)s * DMODEL + d] = o;
    xb[(long)s * DMODEL + d] = (bf16_t)o;
  }
}

// ---- LN over f32 tmp -> xf (f32 master) + xb (bf16 mirror) ---------------
__global__ __launch_bounds__(256) void ln_kernel(
    const float* __restrict__ in, const float* __restrict__ g,
    const float* __restrict__ b, float* __restrict__ xf,
    bf16_t* __restrict__ xb) {
  __shared__ float sred[4];
  int row = blockIdx.x, t = threadIdx.x;
  const float* r = in + (long)row * DMODEL;
  float v[3] = {r[t], r[t + 256], r[t + 512]};
  float mu = blk_sum(v[0] + v[1] + v[2], sred) * (1.0f / 768.0f);
  float ss = 0.f;
#pragma unroll
  for (int j = 0; j < 3; ++j) { v[j] -= mu; ss += v[j] * v[j]; }
  float rs = rsqrtf(blk_sum(ss, sred) * (1.0f / 768.0f) + 1e-5f);
#pragma unroll
  for (int j = 0; j < 3; ++j) {
    int d = t + j * 256;
    float o = v[j] * rs * g[d] + b[d];
    xf[(long)row * DMODEL + d] = o;
    xb[(long)row * DMODEL + d] = (bf16_t)o;
  }
}

// ---- LN over (sum of ns split-K partials + gemm bias + residual xf) ------
// val[d] = sum_z pt[z][row][d] + gb[d] + xf[row][d]; then LN -> xf, xb.
__global__ __launch_bounds__(256) void lnred_kernel(
    const float* __restrict__ pt, int ns, const float* __restrict__ gb,
    const float* __restrict__ g, const float* __restrict__ b,
    float* __restrict__ xf, bf16_t* __restrict__ xb) {
  __shared__ float sred[4];
  const long MN = (long)S_LEN * DMODEL;
  int row = blockIdx.x, t = threadIdx.x;
  long rb = (long)row * DMODEL;
  float v[3];
#pragma unroll
  for (int j = 0; j < 3; ++j) {
    int d = t + j * 256;
    float a = gb[d] + xf[rb + d];
    for (int z = 0; z < ns; ++z) a += pt[(long)z * MN + rb + d];
    v[j] = a;
  }
  float mu = blk_sum(v[0] + v[1] + v[2], sred) * (1.0f / 768.0f);
  float ss = 0.f;
#pragma unroll
  for (int j = 0; j < 3; ++j) { v[j] -= mu; ss += v[j] * v[j]; }
  float rs = rsqrtf(blk_sum(ss, sred) * (1.0f / 768.0f) + 1e-5f);
#pragma unroll
  for (int j = 0; j < 3; ++j) {
    int d = t + j * 256;
    float o = v[j] * rs * g[d] + b[d];
    xf[rb + d] = o;
    xb[rb + d] = (bf16_t)o;
  }
}

// ---- f32 -> bf16 transpose (weights), 64x64 tiles ------------------------
__global__ __launch_bounds__(256) void trc_kernel(const float* __restrict__ src,
                                                  bf16_t* __restrict__ dst,
                                                  int R, int C, long srcStride,
                                                  long dstStride) {
  src += (long)blockIdx.z * srcStride;
  dst += (long)blockIdx.z * dstStride;
  __shared__ float tile[64][65];
  int r0 = blockIdx.y * 64, c0 = blockIdx.x * 64;
  int t = threadIdx.x;
  int tr = t >> 4;
  int tc = (t & 15) * 4;
#pragma unroll
  for (int j = 0; j < 4; ++j) {
    int row = tr + j * 16;
    float4 v = *(const float4*)(src + (long)(r0 + row) * C + c0 + tc);
    tile[row][tc] = v.x; tile[row][tc + 1] = v.y;
    tile[row][tc + 2] = v.z; tile[row][tc + 3] = v.w;
  }
  __syncthreads();
#pragma unroll
  for (int j = 0; j < 4; ++j) {
    int row = tr + j * 16;  // dst row within tile (= src col)
    bf16x4 v;
    v[0] = (bf16_t)tile[tc + 0][row]; v[1] = (bf16_t)tile[tc + 1][row];
    v[2] = (bf16_t)tile[tc + 2][row]; v[3] = (bf16_t)tile[tc + 3][row];
    *(bf16x4*)(dst + (long)(c0 + row) * R + r0 + tc) = v;
  }
}

// ---- bf16 -> bf16 transpose (V), 64x64 tiles ------------------------------
__global__ __launch_bounds__(256) void tr_kernel(const bf16_t* __restrict__ src,
                                                 bf16_t* __restrict__ dst,
                                                 int R, int C) {
  __shared__ bf16_t tile[64][68];
  int r0 = blockIdx.y * 64, c0 = blockIdx.x * 64;
  int t = threadIdx.x;
  int tr = t >> 4;
  int tc = (t & 15) * 4;
#pragma unroll
  for (int j = 0; j < 4; ++j) {
    int row = tr + j * 16;
    bf16x4 v = *(const bf16x4*)(src + (long)(r0 + row) * C + c0 + tc);
    tile[row][tc] = v[0]; tile[row][tc + 1] = v[1];
    tile[row][tc + 2] = v[2]; tile[row][tc + 3] = v[3];
  }
  __syncthreads();
#pragma unroll
  for (int j = 0; j < 4; ++j) {
    int row = tr + j * 16;
    bf16x4 v;
    v[0] = tile[tc + 0][row]; v[1] = tile[tc + 1][row];
    v[2] = tile[tc + 2][row]; v[3] = tile[tc + 3][row];
    *(bf16x4*)(dst + (long)(c0 + row) * R + r0 + tc) = v;
  }
}

// ---- main GEMM: C = A(MxK) * Bt(NxK)^T + bias, 128x128 tile, BK=64 -------
// m97 structure: single 32 KB LDS buffer, global_load_lds width-16 staging,
// 2 barriers per K-step. Relies on >=2 co-resident blocks/CU for overlap
// (32 KB LDS -> up to 5 blocks/CU). Split-K (EP 3) raises small grids to
// 3 blocks/CU. XCD-aware bijective block swizzle (all grids have nwg%8==0).
// EP 0: out = bf16(acc + bias); z = weight set      (QKV)
// EP 1: out = bf16(gelu(acc + bias))                (FF1)
// EP 2: tmp = acc + bias + resf (f32)               (fallback proj/FF2)
// EP 3: tmp[z] = acc (f32 partial); z = K-chunk     (split-K proj/FF2)
template <int EP>
__global__ __launch_bounds__(256) void gemm_kernel(
    const bf16_t* __restrict__ A, const bf16_t* __restrict__ Bt, long btStride,
    const float* b0, const float* b1, const float* b2,
    bf16_t* __restrict__ out, long outStride, const float* __restrict__ resf,
    float* __restrict__ tmp, int M, int N, int K, int kc) {
  int z = blockIdx.z;
  const float* bias = nullptr;
  int kBeg = 0;
  if constexpr (EP == 3) {
    kBeg = z * kc;  // K-chunk
  } else {
    Bt += (long)z * btStride;
    bias = (z == 0) ? b0 : (z == 1 ? b1 : b2);
    out += (long)z * outStride;
  }

  // XCD-aware bijective swizzle (requires nwg % 8 == 0; holds: 192/768)
  int nwg = gridDim.x * gridDim.y;
  int bid = blockIdx.y * gridDim.x + blockIdx.x;
  int swz = (bid & 7) * (nwg >> 3) + (bid >> 3);
  int bx = swz % gridDim.x;
  int by = swz / gridDim.x;

  int tid = threadIdx.x;
  int lane = tid & 63;
  int wave = tid >> 6;
  int wm = (wave >> 1) * 64;
  int wn = (wave & 1) * 64;
  int l15 = lane & 15;
  int g4 = lane >> 4;
  int m0 = by * 128;
  int n0 = bx * 128;

  f32x4 acc[4][4] = {};

  // layout: [k-octet g(0..7)][row(0..127)] x 8 contiguous bf16
  __shared__ __align__(16) bf16_t As[128 * 64];
  __shared__ __align__(16) bf16_t Bs[128 * 64];

  for (int kt = kBeg; kt < kBeg + kc; kt += 64) {
    // stage: 8 x 1KB global_load_lds per wave (A and B tiles)
#pragma unroll
    for (int c = 0; c < 4; ++c) {
      int L0 = c * 256 + wave * 64;   // wave-uniform LDS base (16B units)
      int row = (L0 & 127) + lane;    // lane's source row
      int gg = L0 >> 7;               // k-octet for this issue
      gload_lds16(A + (long)(m0 + row) * K + kt + gg * 8, As + L0 * 8);
      gload_lds16(Bt + (long)(n0 + row) * K + kt + gg * 8, Bs + L0 * 8);
    }
    __syncthreads();  // drains vmcnt(0): staged data visible to all waves
#pragma unroll
    for (int ks = 0; ks < 2; ++ks) {
      bf16x8 af[4], bfr[4];
#pragma unroll
      for (int mt = 0; mt < 4; ++mt)
        af[mt] = *(const bf16x8*)(As + (((ks * 4 + g4) * 128) + wm + mt * 16 + l15) * 8);
#pragma unroll
      for (int nt = 0; nt < 4; ++nt)
        bfr[nt] = *(const bf16x8*)(Bs + (((ks * 4 + g4) * 128) + wn + nt * 16 + l15) * 8);
#pragma unroll
      for (int mt = 0; mt < 4; ++mt)
#pragma unroll
        for (int nt = 0; nt < 4; ++nt)
          acc[mt][nt] = __builtin_amdgcn_mfma_f32_16x16x32_bf16(
              af[mt], bfr[nt], acc[mt][nt], 0, 0, 0);
    }
    __syncthreads();  // all waves done reading As/Bs before next stage
  }

#pragma unroll
  for (int mt = 0; mt < 4; ++mt)
#pragma unroll
    for (int nt = 0; nt < 4; ++nt) {
      int col = n0 + wn + nt * 16 + l15;
      float bval = (EP == 3) ? 0.f : bias[col];
#pragma unroll
      for (int r = 0; r < 4; ++r) {
        int row = m0 + wm + mt * 16 + g4 * 4 + r;
        float v = acc[mt][nt][r] + bval;
        if (EP == 0) {
          out[(long)row * N + col] = (bf16_t)v;
        } else if (EP == 1) {
          float ge = 0.5f * v * (1.0f + erff(v * 0.70710678118654752f));
          out[(long)row * N + col] = (bf16_t)ge;
        } else if (EP == 2) {
          tmp[(long)row * N + col] = v + resf[(long)row * N + col];
        } else {
          tmp[(long)z * ((long)M * N) + (long)row * N + col] = v;
        }
      }
    }
}

// ---- sliding-window flash attention --------------------------------------
// grid (S/32, H), block 64 (1 wave), 32 q-rows per wave. No LDS, no barriers:
// alpha/l broadcasts via __shfl (uniform across g4 after xor-reduce).
// V fragments hoisted to tile top (latency hidden under softmax VALU);
// K fragments explicitly double-buffered across tiles.
#define NEGM 30000.0f
__global__ __launch_bounds__(64) void attn_kernel(
    const bf16_t* __restrict__ q, const bf16_t* __restrict__ k,
    const bf16_t* __restrict__ vt, bf16_t* __restrict__ outb) {
  int qt = blockIdx.x * 32;
  int hcol = blockIdx.y * 64;
  int lane = threadIdx.x;
  int l15 = lane & 15, g4 = lane >> 4;

  // Q fragments (B-operand of St = K @ Q^T), scale 1/8 folded in (exact).
  bf16x8 qf[2][2];
#pragma unroll
  for (int nt = 0; nt < 2; ++nt)
#pragma unroll
    for (int ks = 0; ks < 2; ++ks) {
      bf16x8 t = *(const bf16x8*)(q + (long)(qt + nt * 16 + l15) * DMODEL +
                                  hcol + ks * 32 + g4 * 8);
#pragma unroll
      for (int i = 0; i < 8; ++i) t[i] = (bf16_t)((float)t[i] * 0.125f);
      qf[nt][ks] = t;
    }

  f32x4 o[2][4] = {};   // [qmt][dt]; lane r -> O[q=16qmt+4g4+r][d=16dt+l15]
  float mS[2], lS[2];
#pragma unroll
  for (int nt = 0; nt < 2; ++nt) { mS[nt] = -NEGM; lS[nt] = 0.f; }

  // 64-aligned key window covering [qt-256, qt+31+256]; overshoot is masked.
  int kstart = (qt >= 256) ? ((qt - 256) & ~63) : 0;
  int kend = (qt + 288 + 63) & ~63;
  if (kend > S_LEN) kend = S_LEN;

  // prefetch K fragments of first tile
  bf16x8 kf[4][2];
#pragma unroll
  for (int kt = 0; kt < 4; ++kt)
#pragma unroll
    for (int ks = 0; ks < 2; ++ks)
      kf[kt][ks] = *(const bf16x8*)(k + (long)(kstart + kt * 16 + l15) * DMODEL +
                                    hcol + ks * 32 + g4 * 8);

  for (int kb = kstart; kb < kend; kb += 64) {
    // V fragments for this tile -- independent of QK/softmax; issue early so
    // their latency hides under the softmax VALU work.
    bf16x4 vf[4][4];  // [kt][dt]
#pragma unroll
    for (int kt = 0; kt < 4; ++kt)
#pragma unroll
      for (int dt = 0; dt < 4; ++dt)
        vf[kt][dt] = *(const bf16x4*)(vt + (long)(hcol + dt * 16 + l15) * S_LEN +
                                      kb + kt * 16 + g4 * 4);

    // St = K_chunk @ Q^T -> St[key=16kt+4g4+r][q=16nt+l15]
    f32x4 st[4][2] = {};
    __builtin_amdgcn_s_setprio(1);
#pragma unroll
    for (int kt = 0; kt < 4; ++kt)
#pragma unroll
      for (int nt = 0; nt < 2; ++nt) {
        st[kt][nt] = __builtin_amdgcn_mfma_f32_16x16x32_bf16(
            kf[kt][0], qf[nt][0], st[kt][nt], 0, 0, 0);
        st[kt][nt] = __builtin_amdgcn_mfma_f32_16x16x32_bf16(
            kf[kt][1], qf[nt][1], st[kt][nt], 0, 0, 0);
      }
    __builtin_amdgcn_s_setprio(0);

    // prefetch next tile's K fragments (consumed next iteration)
    int kbn = kb + 64;
    bf16x8 kfn[4][2];
    if (kbn < kend) {
#pragma unroll
      for (int kt = 0; kt < 4; ++kt)
#pragma unroll
        for (int ks = 0; ks < 2; ++ks)
          kfn[kt][ks] = *(const bf16x8*)(k + (long)(kbn + kt * 16 + l15) * DMODEL +
                                         hcol + ks * 32 + g4 * 8);
    }

    // band mask + online softmax stats (per query q = 16nt + l15)
    float alpha[2];
#pragma unroll
    for (int nt = 0; nt < 2; ++nt) {
      int qg = qt + nt * 16 + l15;
      float mx = -NEGM;
#pragma unroll
      for (int kt = 0; kt < 4; ++kt)
#pragma unroll
        for (int r = 0; r < 4; ++r) {
          int kg = kb + kt * 16 + g4 * 4 + r;
          bool valid = (kg >= qg - 256) && (kg <= qg + 256);
          float s = valid ? st[kt][nt][r] : -NEGM;
          st[kt][nt][r] = s;
          mx = fmaxf(mx, s);
        }
      mx = fmaxf(mx, __shfl_xor(mx, 16, 64));
      mx = fmaxf(mx, __shfl_xor(mx, 32, 64));
      float mnew = fmaxf(mS[nt], mx);
      alpha[nt] = exp2f((mS[nt] - mnew) * 1.44269504088896f);
      float ls = 0.f;
#pragma unroll
      for (int kt = 0; kt < 4; ++kt)
#pragma unroll
        for (int r = 0; r < 4; ++r) {
          float p = exp2f((st[kt][nt][r] - mnew) * 1.44269504088896f);
          st[kt][nt][r] = p;
          ls += p;
        }
      ls += __shfl_xor(ls, 16, 64);
      ls += __shfl_xor(ls, 32, 64);
      lS[nt] = lS[nt] * alpha[nt] + ls;
      mS[nt] = mnew;
    }
    // broadcast alpha into O-layout via shfl (alpha uniform across g4; the
    // value for q-row 16*qmt + 4*g4 + r lives at lane l15 = 4*g4 + r)
    f32x4 av[2];
#pragma unroll
    for (int qmt = 0; qmt < 2; ++qmt)
#pragma unroll
      for (int r = 0; r < 4; ++r)
        av[qmt][r] = __shfl(alpha[qmt], g4 * 4 + r, 64);
#pragma unroll
    for (int qmt = 0; qmt < 2; ++qmt)
#pragma unroll
      for (int dt = 0; dt < 4; ++dt)
#pragma unroll
        for (int r = 0; r < 4; ++r) o[qmt][dt][r] *= av[qmt][r];
    // PV: St lanes are already exactly the A-operand of 16x16x16 MFMA.
    __builtin_amdgcn_s_setprio(1);
#pragma unroll
    for (int kt = 0; kt < 4; ++kt) {
      bf16x4 pa[2];
#pragma unroll
      for (int qmt = 0; qmt < 2; ++qmt)
#pragma unroll
        for (int i = 0; i < 4; ++i) pa[qmt][i] = (bf16_t)st[kt][qmt][i];
#pragma unroll
      for (int qmt = 0; qmt < 2; ++qmt)
#pragma unroll
        for (int dt = 0; dt < 4; ++dt)
          o[qmt][dt] = mfma16x16x16(pa[qmt], vf[kt][dt], o[qmt][dt]);
    }
    __builtin_amdgcn_s_setprio(0);
    // roll K double-buffer
    if (kbn < kend) {
#pragma unroll
      for (int kt = 0; kt < 4; ++kt)
#pragma unroll
        for (int ks = 0; ks < 2; ++ks) kf[kt][ks] = kfn[kt][ks];
    }
  }
  // final normalize by l (same shfl broadcast as alpha)
  f32x4 lv[2];
#pragma unroll
  for (int qmt = 0; qmt < 2; ++qmt)
#pragma unroll
    for (int r = 0; r < 4; ++r)
      lv[qmt][r] = __shfl(lS[qmt], g4 * 4 + r, 64);
#pragma unroll
  for (int qmt = 0; qmt < 2; ++qmt)
#pragma unroll
    for (int dt = 0; dt < 4; ++dt)
#pragma unroll
      for (int r = 0; r < 4; ++r)
        outb[(long)(qt + qmt * 16 + g4 * 4 + r) * DMODEL + hcol + dt * 16 +
             l15] = (bf16_t)(o[qmt][dt][r] / lv[qmt][r]);
}

// ---- classifier stage 1: h = relu(pooled @ W1 + b1), parallel ------------
// grid (8, 2): x = 64-col group, y = head (0=century, 1=decade).
// 256 threads: col = t&63 (+group*64), k-chunk (t>>6)*192; LDS reduce by 4.
__global__ __launch_bounds__(256) void cls1_kernel(
    const float* __restrict__ xf, const float* cW1, const float* cb1,
    const float* dW1, const float* db1, float* __restrict__ hws) {
  __shared__ float red[4][64];
  bool dec = (blockIdx.y == 1);
  const float* W1 = dec ? dW1 : cW1;
  const float* B1 = dec ? db1 : cb1;
  float* h = hws + (dec ? 512 : 0);
  int t = threadIdx.x;
  int c = (t & 63) + blockIdx.x * 64;
  int ch = t >> 6;
  float s = 0.f;
  for (int k2 = ch * 192; k2 < ch * 192 + 192; ++k2)
    s += xf[k2] * W1[(long)k2 * 512 + c];
  red[ch][t & 63] = s;
  __syncthreads();
  if (t < 64) {
    int col = t + blockIdx.x * 64;
    float a = red[0][t] + red[1][t] + red[2][t] + red[3][t] + B1[col];
    h[col] = fmaxf(a, 0.f);
  }
}

// ---- classifier stage 2: out = h @ W2 + b2 (tiny) -------------------------
__global__ __launch_bounds__(256) void cls2_kernel(
    const float* __restrict__ hws, const float* cW2, const float* cb2,
    const float* dW2, const float* db2, float* __restrict__ out) {
  __shared__ float sred[4];
  bool dec = (blockIdx.x == 1);
  const float* W2 = dec ? dW2 : cW2;
  const float* B2 = dec ? db2 : cb2;
  const float* h = hws + (dec ? 512 : 0);
  int nout = dec ? 10 : 5;
  float* op = out + (dec ? 5 : 0);
  int t = threadIdx.x;
  float h0 = h[t], h1 = h[t + 256];
  for (int o = 0; o < nout; ++o) {
    float s = h0 * W2[t * nout + o] + h1 * W2[(t + 256) * nout + o];
    float tot = blk_sum(s, sred);
    if (t == 0) op[o] = tot + B2[o];
    __syncthreads();
  }
}

// ---- host orchestration --------------------------------------------------
extern "C" void kernel_launch(void* const* d_in, const int* in_sizes, int n_in,
                              void* d_out, int out_size, void* d_ws,
                              size_t ws_size, hipStream_t stream) {
  const int* ids = (const int*)d_in[0];
  const int* amask = (const int*)d_in[1];
  const float* emb_word = (const float*)d_in[2];
  const float* emb_pos = (const float*)d_in[3];
  const float* emb_type = (const float*)d_in[4];
  const float* emb_g = (const float*)d_in[5];
  const float* emb_b = (const float*)d_in[6];
  const float* Wq = (const float*)d_in[7];
  const float* bq = (const float*)d_in[8];
  const float* Wk = (const float*)d_in[9];
  const float* bk = (const float*)d_in[10];
  const float* Wv = (const float*)d_in[11];
  const float* bv = (const float*)d_in[12];
  const float* Wo = (const float*)d_in[13];
  const float* bo = (const float*)d_in[14];
  const float* ln1g = (const float*)d_in[15];
  const float* ln1b = (const float*)d_in[16];
  const float* W1 = (const float*)d_in[17];
  const float* b1 = (const float*)d_in[18];
  const float* W2 = (const float*)d_in[19];
  const float* b2 = (const float*)d_in[20];
  const float* ln2g = (const float*)d_in[21];
  const float* ln2b = (const float*)d_in[22];
  const float* cW1 = (const float*)d_in[23];
  const float* cb1 = (const float*)d_in[24];
  const float* cW2 = (const float*)d_in[25];
  const float* cb2 = (const float*)d_in[26];
  const float* dW1 = (const float*)d_in[27];
  const float* db1 = (const float*)d_in[28];
  const float* dW2 = (const float*)d_in[29];
  const float* db2 = (const float*)d_in[30];
  float* outp = (float*)d_out;

  const size_t SD = (size_t)S_LEN * DMODEL;
  const size_t DD = (size_t)DMODEL * DMODEL;
  const size_t DF = (size_t)DMODEL * FFDIM;
  const size_t SF = (size_t)S_LEN * FFDIM;

  char* p = (char*)d_ws;
  auto carve = [&](size_t bytes) {
    char* r = p;
    p += (bytes + 255) & ~(size_t)255;
    return (void*)r;
  };

  size_t actsBytes = SD * 2 + SD * 4 + 3 * SD * 2 + SD * 2 + SD * 2 + SF * 2 +
                     SD * 4 + S_LEN * 4 + 16 * 256;
  size_t fullW = (36 * DD + 12 * DD + 24 * DF) * 2 + 16 * 256;
  bool full = ws_size >= actsBytes + fullW;

  bf16_t *qkvt, *wot, *w1t, *w2t;
  if (full) {
    qkvt = (bf16_t*)carve(36 * DD * 2);
    wot = (bf16_t*)carve(12 * DD * 2);
    w1t = (bf16_t*)carve(12 * DF * 2);
    w2t = (bf16_t*)carve(12 * DF * 2);
  } else {
    qkvt = (bf16_t*)carve(3 * DD * 2);
    wot = (bf16_t*)carve(DD * 2);
    w1t = (bf16_t*)carve(DF * 2);
    w2t = (bf16_t*)carve(DF * 2);
  }
  bf16_t* xb = (bf16_t*)carve(SD * 2);
  float* xf = (float*)carve(SD * 4);
  bf16_t* qkv = (bf16_t*)carve(3 * SD * 2);
  bf16_t* vt = (bf16_t*)carve(SD * 2);
  bf16_t* attnb = (bf16_t*)carve(SD * 2);
  bf16_t* hbuf = (bf16_t*)carve(SF * 2);
  float* tmp = (float*)carve(SD * 4);
  int* pids = (int*)carve(S_LEN * 4);
  float* hws = (float*)carve(1024 * 4);  // classifier hidden (2 heads x 512)
  // split-K partial buffer (4 f32 planes); only used if it fits
  float* ptmp = (float*)carve(4 * SD * 4);
  bool haveSplit = ((size_t)(p - (char*)d_ws) <= ws_size);

  posid_kernel<<<1, 256, 0, stream>>>(amask, pids);
  embed_kernel<<<S_LEN, 256, 0, stream>>>(ids, pids, emb_word, emb_pos,
                                          emb_type, emb_g, emb_b, xf, xb);

  if (full) {
    trc_kernel<<<dim3(12, 12, 12), 256, 0, stream>>>(Wq, qkvt, 768, 768, DD, 3 * DD);
    trc_kernel<<<dim3(12, 12, 12), 256, 0, stream>>>(Wk, qkvt + DD, 768, 768, DD, 3 * DD);
    trc_kernel<<<dim3(12, 12, 12), 256, 0, stream>>>(Wv, qkvt + 2 * DD, 768, 768, DD, 3 * DD);
    trc_kernel<<<dim3(12, 12, 12), 256, 0, stream>>>(Wo, wot, 768, 768, DD, DD);
    trc_kernel<<<dim3(48, 12, 12), 256, 0, stream>>>(W1, w1t, 768, 3072, DF, DF);
    trc_kernel<<<dim3(12, 48, 12), 256, 0, stream>>>(W2, w2t, 3072, 768, DF, DF);
  }

  for (int i = 0; i < NLAYER; ++i) {
    const bf16_t *qkvt_i, *wot_i, *w1t_i, *w2t_i;
    if (full) {
      qkvt_i = qkvt + (size_t)i * 3 * DD;
      wot_i = wot + (size_t)i * DD;
      w1t_i = w1t + (size_t)i * DF;
      w2t_i = w2t + (size_t)i * DF;
    } else {
      trc_kernel<<<dim3(12, 12, 1), 256, 0, stream>>>(Wq + (size_t)i * DD, qkvt, 768, 768, 0, 0);
      trc_kernel<<<dim3(12, 12, 1), 256, 0, stream>>>(Wk + (size_t)i * DD, qkvt + DD, 768, 768, 0, 0);
      trc_kernel<<<dim3(12, 12, 1), 256, 0, stream>>>(Wv + (size_t)i * DD, qkvt + 2 * DD, 768, 768, 0, 0);
      trc_kernel<<<dim3(12, 12, 1), 256, 0, stream>>>(Wo + (size_t)i * DD, wot, 768, 768, 0, 0);
      trc_kernel<<<dim3(48, 12, 1), 256, 0, stream>>>(W1 + (size_t)i * DF, w1t, 768, 3072, 0, 0);
      trc_kernel<<<dim3(12, 48, 1), 256, 0, stream>>>(W2 + (size_t)i * DF, w2t, 3072, 768, 0, 0);
      qkvt_i = qkvt; wot_i = wot; w1t_i = w1t; w2t_i = w2t;
    }
    gemm_kernel<0><<<dim3(6, 32, 3), 256, 0, stream>>>(
        xb, qkvt_i, (long)DD, bq + i * 768, bk + i * 768, bv + i * 768, qkv,
        (long)SD, nullptr, nullptr, S_LEN, 768, 768, 768);
    tr_kernel<<<dim3(12, 64, 1), 256, 0, stream>>>(qkv + 2 * SD, vt, 4096, 768);
    attn_kernel<<<dim3(128, 12), 64, 0, stream>>>(qkv, qkv + SD, vt, attnb);
    if (haveSplit) {
      gemm_kernel<3><<<dim3(6, 32, 2), 256, 0, stream>>>(
          attnb, wot_i, 0, nullptr, nullptr, nullptr, nullptr, 0, nullptr,
          ptmp, S_LEN, 768, 768, 384);
      lnred_kernel<<<S_LEN, 256, 0, stream>>>(ptmp, 2, bo + i * 768,
                                              ln1g + i * 768, ln1b + i * 768,
                                              xf, xb);
    } else {
      gemm_kernel<2><<<dim3(6, 32, 1), 256, 0, stream>>>(
          attnb, wot_i, 0, bo + i * 768, nullptr, nullptr, nullptr, 0, xf, tmp,
          S_LEN, 768, 768, 768);
      ln_kernel<<<S_LEN, 256, 0, stream>>>(tmp, ln1g + i * 768, ln1b + i * 768,
                                           xf, xb);
    }
    gemm_kernel<1><<<dim3(24, 32, 1), 256, 0, stream>>>(
        xb, w1t_i, 0, b1 + (size_t)i * FFDIM, nullptr, nullptr, hbuf, 0,
        nullptr, nullptr, S_LEN, FFDIM, 768, 768);
    if (haveSplit) {
      gemm_kernel<3><<<dim3(6, 32, 4), 256, 0, stream>>>(
          hbuf, w2t_i, 0, nullptr, nullptr, nullptr, nullptr, 0, nullptr,
          ptmp, S_LEN, 768, 3072, 768);
      lnred_kernel<<<S_LEN, 256, 0, stream>>>(ptmp, 4, b2 + i * 768,
                                              ln2g + i * 768, ln2b + i * 768,
                                              xf, xb);
    } else {
      gemm_kernel<2><<<dim3(6, 32, 1), 256, 0, stream>>>(
          hbuf, w2t_i, 0, b2 + i * 768, nullptr, nullptr, nullptr, 0, xf, tmp,
          S_LEN, 768, 3072, 3072);
      ln_kernel<<<S_LEN, 256, 0, stream>>>(tmp, ln2g + i * 768, ln2b + i * 768,
                                           xf, xb);
    }
  }
  cls1_kernel<<<dim3(8, 2), 256, 0, stream>>>(xf, cW1, cb1, dW1, db1, hws);
  cls2_kernel<<<2, 256, 0, stream>>>(hws, cW2, cb2, dW2, db2, outp);
}